// Round 8
// baseline (562.807 us; speedup 1.0000x reference)
//
#include <hip/hip_runtime.h>
#include <hip/hip_bf16.h>
#include <cstdint>

// ---------------------------------------------------------------------------
// GAT 3-layer forward. N=50000, E=800000, H=4, D=64 (FEAT = H*D = 256 = F_IN).
// R8: (1) per-edge e[] precomputed in CSR order (cuts agg's random el-gather +
//     lrelu off the critical chain); (2) all three agg layers gather bf16;
//     (3) A-operand hi/lo bf16 split hoisted out of GEMM (fsplit once for
//     features; agg epilogue emits hi/lo directly for hidden layers).
// ---------------------------------------------------------------------------

#define FEAT 256
#define NHEAD 4

typedef short short8 __attribute__((ext_vector_type(8)));
typedef float f32x4 __attribute__((ext_vector_type(4)));

__device__ __forceinline__ ushort f2bf(float v) {
    uint u = __float_as_uint(v);
    uint r = (u + 0x7fffu + ((u >> 16) & 1u)) >> 16;
    return (ushort)r;
}
__device__ __forceinline__ float bf2f(ushort h) {
    return __uint_as_float(((uint)h) << 16);
}

// ---------------- CSR build ----------------
__global__ void hist_kernel(const int* __restrict__ dst, int* __restrict__ deg, int E) {
    int e = blockIdx.x * 256 + threadIdx.x;
    if (e < E) atomicAdd(&deg[dst[e]], 1);
}

__global__ void scan_block(const int* __restrict__ deg, int* __restrict__ offs,
                           int* __restrict__ bsums, int n) {
    __shared__ int s[256];
    int i = blockIdx.x * 256 + threadIdx.x;
    int v = (i < n) ? deg[i] : 0;
    s[threadIdx.x] = v; __syncthreads();
    #pragma unroll
    for (int off = 1; off < 256; off <<= 1) {
        int t = (threadIdx.x >= off) ? s[threadIdx.x - off] : 0;
        __syncthreads();
        s[threadIdx.x] += t;
        __syncthreads();
    }
    if (i < n) offs[i] = s[threadIdx.x] - v;
    if (threadIdx.x == 255) bsums[blockIdx.x] = s[255];
}

__global__ void scan_sums(int* __restrict__ bsums, int nb) {
    __shared__ int s[256];
    int v = (threadIdx.x < nb) ? bsums[threadIdx.x] : 0;
    s[threadIdx.x] = v; __syncthreads();
    #pragma unroll
    for (int off = 1; off < 256; off <<= 1) {
        int t = (threadIdx.x >= off) ? s[threadIdx.x - off] : 0;
        __syncthreads();
        s[threadIdx.x] += t;
        __syncthreads();
    }
    if (threadIdx.x < nb) bsums[threadIdx.x] = s[threadIdx.x] - v;
}

__global__ void scan_add(int* __restrict__ offs, int* __restrict__ cursor,
                         const int* __restrict__ bsums, int n, int total) {
    int i = blockIdx.x * 256 + threadIdx.x;
    if (i < n) {
        int o = offs[i] + bsums[i >> 8];
        offs[i] = o;
        cursor[i] = o;
    }
    if (i == 0) offs[n] = total;
}

__global__ void scatter_kernel(const int* __restrict__ src, const int* __restrict__ dst,
                               int* __restrict__ cursor, int* __restrict__ csr_src,
                               int* __restrict__ csr_dst, int E) {
    int e = blockIdx.x * 256 + threadIdx.x;
    if (e < E) {
        int d = dst[e];
        int pos = atomicAdd(&cursor[d], 1);
        csr_src[pos] = src[e];
        csr_dst[pos] = d;
    }
}

// ---------------- W prep: split f32 W[k][n] -> bf16 hi/lo, transposed [n][k] ----
__global__ void wprep_kernel(const float* __restrict__ W,
                             ushort* __restrict__ Wh, ushort* __restrict__ Wl) {
    int n = blockIdx.x;
    int k = threadIdx.x;
    float v = W[(size_t)k * FEAT + n];
    ushort h = f2bf(v);
    float r = v - bf2f(h);
    Wh[(size_t)n * FEAT + k] = h;
    Wl[(size_t)n * FEAT + k] = f2bf(r);
}

// ---------------- fsplit: f32 row-major -> hi/lo bf16 (elementwise) ----------------
__global__ void fsplit_kernel(const float* __restrict__ A, ushort* __restrict__ Ah,
                              ushort* __restrict__ Al, int total8) {
    int i = blockIdx.x * 256 + threadIdx.x;
    if (i >= total8) return;
    const float4* p = (const float4*)(A + (size_t)i * 8);
    float4 a = p[0], b = p[1];
    float v[8] = {a.x, a.y, a.z, a.w, b.x, b.y, b.z, b.w};
    ushort hi[8], lo[8];
    #pragma unroll
    for (int t = 0; t < 8; ++t) {
        hi[t] = f2bf(v[t]);
        lo[t] = f2bf(v[t] - bf2f(hi[t]));
    }
    *(short8*)(Ah + (size_t)i * 8) = *(short8*)hi;
    *(short8*)(Al + (size_t)i * 8) = *(short8*)lo;
}

// ---------------- GEMM: C[M,256] = (Ah+Al)[M,256] @ (Wh+Wl), bf16x3 MFMA ----------
#define GBM 128
#define GBN 128
#define GBK 32
#define LDK 40   // padded K stride (bf16 elems): 80 B rows

__global__ __launch_bounds__(256) void gemm_bf16x3(const ushort* __restrict__ Ahg,
                                                   const ushort* __restrict__ Alg,
                                                   const ushort* __restrict__ Wh,
                                                   const ushort* __restrict__ Wl,
                                                   float* __restrict__ C, int M) {
    __shared__ ushort Ah[GBM][LDK];
    __shared__ ushort Al[GBM][LDK];
    __shared__ ushort Bh[GBN][LDK];
    __shared__ ushort Bl[GBN][LDK];

    const int tid  = threadIdx.x;
    const int lane = tid & 63;
    const int wid  = tid >> 6;
    const int wm   = (wid >> 1) * 64;
    const int wn   = (wid & 1) * 64;
    const int row0 = blockIdx.x * GBM;
    const int col0 = blockIdx.y * GBN;

    const int ar = tid >> 1;              // A stage row 0..127
    const int aq = (tid & 1) * 16;        // A stage k offset 0/16
    const int bn = tid & 127;             // W stage col(n) 0..127
    const int bq = (tid >> 7) * 16;       // W stage k offset 0/16

    const int fr = lane & 15;
    const int fk = (lane >> 4) * 8;

    f32x4 acc[4][4];
    #pragma unroll
    for (int i = 0; i < 4; ++i)
        #pragma unroll
        for (int j = 0; j < 4; ++j) {
            f32x4 z = {0.f, 0.f, 0.f, 0.f};
            acc[i][j] = z;
        }

    const short8 z8 = {0, 0, 0, 0, 0, 0, 0, 0};

    for (int k0 = 0; k0 < FEAT; k0 += GBK) {
        short8 ah0, ah1, al0, al1;
        if (row0 + ar < M) {
            const short8* pH = (const short8*)(Ahg + (size_t)(row0 + ar) * FEAT + k0 + aq);
            const short8* pL = (const short8*)(Alg + (size_t)(row0 + ar) * FEAT + k0 + aq);
            ah0 = pH[0]; ah1 = pH[1];
            al0 = pL[0]; al1 = pL[1];
        } else {
            ah0 = ah1 = al0 = al1 = z8;
        }
        const short8* Whp = (const short8*)(Wh + (size_t)(col0 + bn) * FEAT + k0 + bq);
        const short8* Wlp = (const short8*)(Wl + (size_t)(col0 + bn) * FEAT + k0 + bq);
        short8 wh0 = Whp[0], wh1 = Whp[1];
        short8 wl0 = Wlp[0], wl1 = Wlp[1];

        __syncthreads();

        *(short8*)&Ah[ar][aq]     = ah0;
        *(short8*)&Ah[ar][aq + 8] = ah1;
        *(short8*)&Al[ar][aq]     = al0;
        *(short8*)&Al[ar][aq + 8] = al1;
        *(short8*)&Bh[bn][bq]     = wh0;
        *(short8*)&Bh[bn][bq + 8] = wh1;
        *(short8*)&Bl[bn][bq]     = wl0;
        *(short8*)&Bl[bn][bq + 8] = wl1;

        __syncthreads();

        short8 afh[4], afl[4], bfh[4], bfl[4];
        #pragma unroll
        for (int t = 0; t < 4; ++t) {
            afh[t] = *(const short8*)&Ah[wm + t * 16 + fr][fk];
            afl[t] = *(const short8*)&Al[wm + t * 16 + fr][fk];
            bfh[t] = *(const short8*)&Bh[wn + t * 16 + fr][fk];
            bfl[t] = *(const short8*)&Bl[wn + t * 16 + fr][fk];
        }
        #pragma unroll
        for (int mt = 0; mt < 4; ++mt)
            #pragma unroll
            for (int nt = 0; nt < 4; ++nt) {
                acc[mt][nt] = __builtin_amdgcn_mfma_f32_16x16x32_bf16(
                    afh[mt], bfh[nt], acc[mt][nt], 0, 0, 0);
                acc[mt][nt] = __builtin_amdgcn_mfma_f32_16x16x32_bf16(
                    afh[mt], bfl[nt], acc[mt][nt], 0, 0, 0);
                acc[mt][nt] = __builtin_amdgcn_mfma_f32_16x16x32_bf16(
                    afl[mt], bfh[nt], acc[mt][nt], 0, 0, 0);
            }
    }

    #pragma unroll
    for (int mt = 0; mt < 4; ++mt) {
        #pragma unroll
        for (int r = 0; r < 4; ++r) {
            int row = row0 + wm + mt * 16 + (lane >> 4) * 4 + r;
            if (row < M) {
                #pragma unroll
                for (int nt = 0; nt < 4; ++nt) {
                    C[(size_t)row * FEAT + col0 + wn + nt * 16 + fr] = acc[mt][nt][r];
                }
            }
        }
    }
}

// ---------------- el/er + bf16 copy of feat ----------------
__global__ __launch_bounds__(256) void elr_kernel(const float* __restrict__ feat,
                                                  const float* __restrict__ al,
                                                  const float* __restrict__ ar,
                                                  float* __restrict__ el,
                                                  float* __restrict__ er,
                                                  ushort* __restrict__ featB, int n) {
    int node = blockIdx.x * 4 + (threadIdx.x >> 6);
    if (node >= n) return;
    int lane = threadIdx.x & 63;
    int f = lane * 4;
    float4 v = *(const float4*)(feat + (size_t)node * FEAT + f);
    ushort4 b;
    b.x = f2bf(v.x); b.y = f2bf(v.y); b.z = f2bf(v.z); b.w = f2bf(v.w);
    *(ushort4*)(featB + (size_t)node * FEAT + f) = b;
    float4 a = *(const float4*)(al + f);
    float4 r = *(const float4*)(ar + f);
    float pl = v.x * a.x + v.y * a.y + v.z * a.z + v.w * a.w;
    float pr = v.x * r.x + v.y * r.y + v.z * r.z + v.w * r.w;
    #pragma unroll
    for (int off = 1; off < 16; off <<= 1) {
        pl += __shfl_xor(pl, off, 64);
        pr += __shfl_xor(pr, off, 64);
    }
    if ((lane & 15) == 0) {
        int h = lane >> 4;
        el[node * NHEAD + h] = pl;
        er[node * NHEAD + h] = pr;
    }
}

// ---------------- eprep: per-edge e = lrelu(el[src]+er[dst]) in CSR order ----------
__global__ __launch_bounds__(256) void eprep_kernel(const int* __restrict__ csr_src,
                                                    const int* __restrict__ csr_dst,
                                                    const float* __restrict__ el,
                                                    const float* __restrict__ er,
                                                    float* __restrict__ eArr, int E) {
    int i = blockIdx.x * 256 + threadIdx.x;
    if (i >= E) return;
    int s = csr_src[i], d = csr_dst[i];
    float4 a = *(const float4*)(el + (size_t)s * NHEAD);
    float4 b = *(const float4*)(er + (size_t)d * NHEAD);
    float4 e;
    e.x = a.x + b.x; e.x = (e.x > 0.f) ? e.x : 0.2f * e.x;
    e.y = a.y + b.y; e.y = (e.y > 0.f) ? e.y : 0.2f * e.y;
    e.z = a.z + b.z; e.z = (e.z > 0.f) ? e.z : 0.2f * e.z;
    e.w = a.w + b.w; e.w = (e.w > 0.f) ? e.w : 0.2f * e.w;
    *(float4*)(eArr + (size_t)i * NHEAD) = e;
}

// ---------------- online-softmax aggregate over bf16 feats ----------------
// outF != nullptr: write f32 (final layer). Else write hi/lo bf16 split (hidden).
__global__ __launch_bounds__(256) void agg_kernel2(const ushort* __restrict__ featB,
                                                   const float* __restrict__ eArr,
                                                   const int* __restrict__ offs,
                                                   const int* __restrict__ csr_src,
                                                   const float* __restrict__ bias,
                                                   float* __restrict__ outF,
                                                   ushort* __restrict__ outH,
                                                   ushort* __restrict__ outL,
                                                   int act, int n) {
    int node = blockIdx.x * 4 + (threadIdx.x >> 6);
    if (node >= n) return;
    int lane = threadIdx.x & 63;
    int h = lane >> 4;
    int j16 = lane & 15;
    int f = lane * 4;
    int start = offs[node];
    int deg = offs[node + 1] - start;

    float m = -1e30f, ssum = 0.f;
    float acc0 = 0.f, acc1 = 0.f, acc2 = 0.f, acc3 = 0.f;
    int sidx = (j16 < deg) ? csr_src[start + j16] : 0;
    float ev = (j16 < deg) ? eArr[(size_t)(start + j16) * NHEAD + h] : -1e30f;

    for (int p0 = 0; p0 < deg; p0 += 16) {
        int pn = p0 + 16 + j16;
        int sidx_nx = (pn < deg) ? csr_src[start + pn] : 0;
        float ev_nx = (pn < deg) ? eArr[(size_t)(start + pn) * NHEAD + h] : -1e30f;
        float cm = ev;
        #pragma unroll
        for (int o = 1; o < 16; o <<= 1) cm = fmaxf(cm, __shfl_xor(cm, o, 64));
        float newm = fmaxf(m, cm);
        float sc = __expf(m - newm);
        m = newm;
        ssum *= sc; acc0 *= sc; acc1 *= sc; acc2 *= sc; acc3 *= sc;
        float w = __expf(ev - m);   // masked lanes: exp(-inf) = 0
        ssum += w;
        int cnt = min(16, deg - p0);
        if (cnt == 16) {
            #pragma unroll
            for (int j = 0; j < 16; ++j) {
                float wj = __shfl(w, j, 16);
                int sj = __shfl(sidx, j, 16);
                ushort4 v = *(const ushort4*)(featB + (size_t)sj * FEAT + f);
                acc0 = fmaf(wj, bf2f(v.x), acc0);
                acc1 = fmaf(wj, bf2f(v.y), acc1);
                acc2 = fmaf(wj, bf2f(v.z), acc2);
                acc3 = fmaf(wj, bf2f(v.w), acc3);
            }
        } else {
            for (int j = 0; j < cnt; ++j) {
                float wj = __shfl(w, j, 16);
                int sj = __shfl(sidx, j, 16);
                ushort4 v = *(const ushort4*)(featB + (size_t)sj * FEAT + f);
                acc0 = fmaf(wj, bf2f(v.x), acc0);
                acc1 = fmaf(wj, bf2f(v.y), acc1);
                acc2 = fmaf(wj, bf2f(v.z), acc2);
                acc3 = fmaf(wj, bf2f(v.w), acc3);
            }
        }
        sidx = sidx_nx;
        ev = ev_nx;
    }
    float st = ssum;
    #pragma unroll
    for (int o = 1; o < 16; o <<= 1) st += __shfl_xor(st, o, 64);
    float inv = 1.f / fmaxf(st, 1e-9f);
    float4 b4 = *(const float4*)(bias + f);
    float o0 = fmaf(acc0, inv, b4.x);
    float o1 = fmaf(acc1, inv, b4.y);
    float o2 = fmaf(acc2, inv, b4.z);
    float o3 = fmaf(acc3, inv, b4.w);
    if (act) {
        o0 = (o0 > 0.f) ? o0 : expm1f(o0);
        o1 = (o1 > 0.f) ? o1 : expm1f(o1);
        o2 = (o2 > 0.f) ? o2 : expm1f(o2);
        o3 = (o3 > 0.f) ? o3 : expm1f(o3);
    }
    if (outF) {
        *((float4*)(outF + (size_t)node * FEAT + f)) = make_float4(o0, o1, o2, o3);
    } else {
        ushort4 hh, ll;
        hh.x = f2bf(o0); ll.x = f2bf(o0 - bf2f(hh.x));
        hh.y = f2bf(o1); ll.y = f2bf(o1 - bf2f(hh.y));
        hh.z = f2bf(o2); ll.z = f2bf(o2 - bf2f(hh.z));
        hh.w = f2bf(o3); ll.w = f2bf(o3 - bf2f(hh.w));
        *(ushort4*)(outH + (size_t)node * FEAT + f) = hh;
        *(ushort4*)(outL + (size_t)node * FEAT + f) = ll;
    }
}

// ---------------------------------------------------------------------------
extern "C" void kernel_launch(void* const* d_in, const int* in_sizes, int n_in,
                              void* d_out, int out_size, void* d_ws, size_t ws_size,
                              hipStream_t stream) {
    const float* features = (const float*)d_in[0];
    const int*   src      = (const int*)d_in[1];
    const int*   dst      = (const int*)d_in[2];
    const int N = in_sizes[0] / FEAT;
    const int E = in_sizes[1];

    // ---- carve workspace (~150 MB) ----
    char* ws = (char*)d_ws;
    size_t off = 0;
    auto carve = [&](size_t bytes) -> void* {
        void* p = ws + off;
        off = (off + bytes + 255) & ~(size_t)255;
        return p;
    };
    int*    deg     = (int*)carve((size_t)N * 4);
    int*    offs    = (int*)carve((size_t)(N + 1) * 4);
    int*    cursor  = (int*)carve((size_t)N * 4);
    int*    bsums   = (int*)carve(4096);
    int*    csr_src = (int*)carve((size_t)E * 4);
    int*    csr_dst = (int*)carve((size_t)E * 4);
    float*  eArr    = (float*)carve((size_t)E * NHEAD * 4);
    float*  el      = (float*)carve((size_t)N * NHEAD * 4);
    float*  er      = (float*)carve((size_t)N * NHEAD * 4);
    float*  featX   = (float*)carve((size_t)N * FEAT * 4);
    ushort* featB   = (ushort*)carve((size_t)N * FEAT * 2);
    ushort* Ah_buf  = (ushort*)carve((size_t)N * FEAT * 2);   // features split, then hidden split
    ushort* Al_buf  = (ushort*)carve((size_t)N * FEAT * 2);
    ushort* Wh[3], *Wl[3];
    for (int i = 0; i < 3; ++i) {
        Wh[i] = (ushort*)carve((size_t)FEAT * FEAT * 2);
        Wl[i] = (ushort*)carve((size_t)FEAT * FEAT * 2);
    }

    const int nbE = (E + 255) / 256;
    const int nbN = (N + 255) / 256;

    // ---- CSR build + W prep + feature split (graph/weights static) ----
    hipMemsetAsync(deg, 0, (size_t)N * 4, stream);
    hist_kernel<<<nbE, 256, 0, stream>>>(dst, deg, E);
    scan_block<<<nbN, 256, 0, stream>>>(deg, offs, bsums, N);
    scan_sums<<<1, 256, 0, stream>>>(bsums, nbN);
    scan_add<<<nbN, 256, 0, stream>>>(offs, cursor, bsums, N, E);
    scatter_kernel<<<nbE, 256, 0, stream>>>(src, dst, cursor, csr_src, csr_dst, E);
    wprep_kernel<<<FEAT, FEAT, 0, stream>>>((const float*)d_in[3],  Wh[0], Wl[0]);
    wprep_kernel<<<FEAT, FEAT, 0, stream>>>((const float*)d_in[7],  Wh[1], Wl[1]);
    wprep_kernel<<<FEAT, FEAT, 0, stream>>>((const float*)d_in[11], Wh[2], Wl[2]);
    const int total8 = N * FEAT / 8;
    fsplit_kernel<<<(total8 + 255) / 256, 256, 0, stream>>>(features, Ah_buf, Al_buf, total8);

    dim3 ggrid((N + GBM - 1) / GBM, FEAT / GBN);
    const int nodeBlocks = (N + 3) / 4;

    // ---- layer 1 ----
    gemm_bf16x3<<<ggrid, 256, 0, stream>>>(Ah_buf, Al_buf, Wh[0], Wl[0], featX, N);
    elr_kernel<<<nodeBlocks, 256, 0, stream>>>(featX, (const float*)d_in[4],
                                               (const float*)d_in[5], el, er, featB, N);
    eprep_kernel<<<nbE, 256, 0, stream>>>(csr_src, csr_dst, el, er, eArr, E);
    agg_kernel2<<<nodeBlocks, 256, 0, stream>>>(featB, eArr, offs, csr_src,
                                                (const float*)d_in[6],
                                                (float*)nullptr, Ah_buf, Al_buf, 1, N);
    // ---- layer 2 ----
    gemm_bf16x3<<<ggrid, 256, 0, stream>>>(Ah_buf, Al_buf, Wh[1], Wl[1], featX, N);
    elr_kernel<<<nodeBlocks, 256, 0, stream>>>(featX, (const float*)d_in[8],
                                               (const float*)d_in[9], el, er, featB, N);
    eprep_kernel<<<nbE, 256, 0, stream>>>(csr_src, csr_dst, el, er, eArr, E);
    agg_kernel2<<<nodeBlocks, 256, 0, stream>>>(featB, eArr, offs, csr_src,
                                                (const float*)d_in[10],
                                                (float*)nullptr, Ah_buf, Al_buf, 1, N);
    // ---- layer 3 ----
    gemm_bf16x3<<<ggrid, 256, 0, stream>>>(Ah_buf, Al_buf, Wh[2], Wl[2], featX, N);
    elr_kernel<<<nodeBlocks, 256, 0, stream>>>(featX, (const float*)d_in[12],
                                               (const float*)d_in[13], el, er, featB, N);
    eprep_kernel<<<nbE, 256, 0, stream>>>(csr_src, csr_dst, el, er, eArr, E);
    agg_kernel2<<<nodeBlocks, 256, 0, stream>>>(featB, eArr, offs, csr_src,
                                                (const float*)d_in[14],
                                                (float*)d_out, (ushort*)nullptr, (ushort*)nullptr, 0, N);
}

// Round 10
// 517.956 us; speedup vs baseline: 1.0866x; 1.0866x over previous
//
#include <hip/hip_runtime.h>
#include <hip/hip_bf16.h>
#include <cstdint>

// ---------------------------------------------------------------------------
// GAT 3-layer forward. N=50000, E=800000, H=4, D=64 (FEAT = H*D = 256 = F_IN).
// R9: (1) revert eprep/eArr (R8 post-mortem: net loss; el gather is L2-resident
//     and cheap); (2) GEMM tile 64x256 = full width, A read once, el/er + bf16
//     featB fused into GEMM epilogue (wave w == head w); elr + featX eliminated;
//     (3) agg: R7-structure online softmax, bf16 gather all layers, epilogue
//     emits hi/lo split (hidden) or f32 d_out (final).
// ---------------------------------------------------------------------------

#define FEAT 256
#define NHEAD 4

typedef short short8 __attribute__((ext_vector_type(8)));
typedef float f32x4 __attribute__((ext_vector_type(4)));

__device__ __forceinline__ ushort f2bf(float v) {
    uint u = __float_as_uint(v);
    uint r = (u + 0x7fffu + ((u >> 16) & 1u)) >> 16;
    return (ushort)r;
}
__device__ __forceinline__ float bf2f(ushort h) {
    return __uint_as_float(((uint)h) << 16);
}

// ---------------- CSR build ----------------
__global__ void hist_kernel(const int* __restrict__ dst, int* __restrict__ deg, int E) {
    int e = blockIdx.x * 256 + threadIdx.x;
    if (e < E) atomicAdd(&deg[dst[e]], 1);
}

__global__ void scan_block(const int* __restrict__ deg, int* __restrict__ offs,
                           int* __restrict__ bsums, int n) {
    __shared__ int s[256];
    int i = blockIdx.x * 256 + threadIdx.x;
    int v = (i < n) ? deg[i] : 0;
    s[threadIdx.x] = v; __syncthreads();
    #pragma unroll
    for (int off = 1; off < 256; off <<= 1) {
        int t = (threadIdx.x >= off) ? s[threadIdx.x - off] : 0;
        __syncthreads();
        s[threadIdx.x] += t;
        __syncthreads();
    }
    if (i < n) offs[i] = s[threadIdx.x] - v;
    if (threadIdx.x == 255) bsums[blockIdx.x] = s[255];
}

__global__ void scan_sums(int* __restrict__ bsums, int nb) {
    __shared__ int s[256];
    int v = (threadIdx.x < nb) ? bsums[threadIdx.x] : 0;
    s[threadIdx.x] = v; __syncthreads();
    #pragma unroll
    for (int off = 1; off < 256; off <<= 1) {
        int t = (threadIdx.x >= off) ? s[threadIdx.x - off] : 0;
        __syncthreads();
        s[threadIdx.x] += t;
        __syncthreads();
    }
    if (threadIdx.x < nb) bsums[threadIdx.x] = s[threadIdx.x] - v;
}

__global__ void scan_add(int* __restrict__ offs, int* __restrict__ cursor,
                         const int* __restrict__ bsums, int n, int total) {
    int i = blockIdx.x * 256 + threadIdx.x;
    if (i < n) {
        int o = offs[i] + bsums[i >> 8];
        offs[i] = o;
        cursor[i] = o;
    }
    if (i == 0) offs[n] = total;
}

__global__ void scatter_kernel(const int* __restrict__ src, const int* __restrict__ dst,
                               int* __restrict__ cursor, int* __restrict__ csr_src, int E) {
    int e = blockIdx.x * 256 + threadIdx.x;
    if (e < E) {
        int d = dst[e];
        int pos = atomicAdd(&cursor[d], 1);
        csr_src[pos] = src[e];
    }
}

// ---------------- W prep: split f32 W[k][n] -> bf16 hi/lo, transposed [n][k] ----
__global__ void wprep_kernel(const float* __restrict__ W,
                             ushort* __restrict__ Wh, ushort* __restrict__ Wl) {
    int n = blockIdx.x;
    int k = threadIdx.x;
    float v = W[(size_t)k * FEAT + n];
    ushort h = f2bf(v);
    float r = v - bf2f(h);
    Wh[(size_t)n * FEAT + k] = h;
    Wl[(size_t)n * FEAT + k] = f2bf(r);
}

// ---------------- fsplit: f32 row-major -> hi/lo bf16 (elementwise) ----------------
__global__ void fsplit_kernel(const float* __restrict__ A, ushort* __restrict__ Ah,
                              ushort* __restrict__ Al, int total8) {
    int i = blockIdx.x * 256 + threadIdx.x;
    if (i >= total8) return;
    const float4* p = (const float4*)(A + (size_t)i * 8);
    float4 a = p[0], b = p[1];
    float v[8] = {a.x, a.y, a.z, a.w, b.x, b.y, b.z, b.w};
    ushort hi[8], lo[8];
    #pragma unroll
    for (int t = 0; t < 8; ++t) {
        hi[t] = f2bf(v[t]);
        lo[t] = f2bf(v[t] - bf2f(hi[t]));
    }
    *(short8*)(Ah + (size_t)i * 8) = *(short8*)hi;
    *(short8*)(Al + (size_t)i * 8) = *(short8*)lo;
}

// ---------------- fused GEMM 64x256 + el/er + bf16 featB epilogue ----------------
// feat = (Ah+Al) @ (Wh+Wl); featB = bf16(feat); el/er = head-dot with al/ar.
// 4 waves; wave w owns cols [64w, 64w+64) == head w (all 64 rows of the tile).
#define GBM 64
#define GBK 32
#define LDK 40   // padded K stride in ushorts (80 B rows)

__global__ __launch_bounds__(256) void gemm_fused(const ushort* __restrict__ Ahg,
                                                  const ushort* __restrict__ Alg,
                                                  const ushort* __restrict__ Whg,
                                                  const ushort* __restrict__ Wlg,
                                                  const float* __restrict__ alv,
                                                  const float* __restrict__ arv,
                                                  ushort* __restrict__ featB,
                                                  float* __restrict__ el,
                                                  float* __restrict__ er, int M) {
    __shared__ ushort Ah[GBM][LDK];
    __shared__ ushort Al[GBM][LDK];
    __shared__ ushort Bh[FEAT][LDK];
    __shared__ ushort Bl[FEAT][LDK];

    const int tid  = threadIdx.x;
    const int lane = tid & 63;
    const int wid  = tid >> 6;          // wave == head == col block
    const int row0 = blockIdx.x * GBM;

    const int arow = tid >> 2;          // A stage row 0..63
    const int achk = (tid & 3) * 8;     // A stage k chunk (ushort offset)
    const int bcol = tid;               // B stage col 0..255

    const int fr = lane & 15;
    const int fk = (lane >> 4) * 8;
    const int q  = lane >> 4;

    f32x4 acc[4][4];
    #pragma unroll
    for (int i = 0; i < 4; ++i)
        #pragma unroll
        for (int j = 0; j < 4; ++j) {
            f32x4 z = {0.f, 0.f, 0.f, 0.f};
            acc[i][j] = z;
        }

    const short8 z8 = {0, 0, 0, 0, 0, 0, 0, 0};

    for (int k0 = 0; k0 < FEAT; k0 += GBK) {
        // global loads
        short8 a_h, a_l;
        if (row0 + arow < M) {
            a_h = *(const short8*)(Ahg + (size_t)(row0 + arow) * FEAT + k0 + achk);
            a_l = *(const short8*)(Alg + (size_t)(row0 + arow) * FEAT + k0 + achk);
        } else {
            a_h = z8; a_l = z8;
        }
        short8 b_h[4], b_l[4];
        #pragma unroll
        for (int c = 0; c < 4; ++c) {
            b_h[c] = *(const short8*)(Whg + (size_t)bcol * FEAT + k0 + c * 8);
            b_l[c] = *(const short8*)(Wlg + (size_t)bcol * FEAT + k0 + c * 8);
        }

        __syncthreads();
        *(short8*)&Ah[arow][achk] = a_h;
        *(short8*)&Al[arow][achk] = a_l;
        #pragma unroll
        for (int c = 0; c < 4; ++c) {
            *(short8*)&Bh[bcol][c * 8] = b_h[c];
            *(short8*)&Bl[bcol][c * 8] = b_l[c];
        }
        __syncthreads();

        short8 bfh[4], bfl[4];
        #pragma unroll
        for (int nt = 0; nt < 4; ++nt) {
            bfh[nt] = *(const short8*)&Bh[wid * 64 + nt * 16 + fr][fk];
            bfl[nt] = *(const short8*)&Bl[wid * 64 + nt * 16 + fr][fk];
        }
        #pragma unroll
        for (int mt = 0; mt < 4; ++mt) {
            short8 afh = *(const short8*)&Ah[mt * 16 + fr][fk];
            short8 afl = *(const short8*)&Al[mt * 16 + fr][fk];
            #pragma unroll
            for (int nt = 0; nt < 4; ++nt) {
                acc[mt][nt] = __builtin_amdgcn_mfma_f32_16x16x32_bf16(
                    afh, bfh[nt], acc[mt][nt], 0, 0, 0);
                acc[mt][nt] = __builtin_amdgcn_mfma_f32_16x16x32_bf16(
                    afh, bfl[nt], acc[mt][nt], 0, 0, 0);
                acc[mt][nt] = __builtin_amdgcn_mfma_f32_16x16x32_bf16(
                    afl, bfh[nt], acc[mt][nt], 0, 0, 0);
            }
        }
    }

    // ---- epilogue: featB (bf16) + el/er for this wave's head ----
    float al4[4], ar4[4];
    #pragma unroll
    for (int nt = 0; nt < 4; ++nt) {
        al4[nt] = alv[wid * 64 + nt * 16 + fr];
        ar4[nt] = arv[wid * 64 + nt * 16 + fr];
    }
    #pragma unroll
    for (int mt = 0; mt < 4; ++mt) {
        #pragma unroll
        for (int r = 0; r < 4; ++r) {
            int row = row0 + mt * 16 + q * 4 + r;
            bool ok = row < M;
            float pl = 0.f, pr = 0.f;
            #pragma unroll
            for (int nt = 0; nt < 4; ++nt) {
                float v = acc[mt][nt][r];
                if (ok) featB[(size_t)row * FEAT + wid * 64 + nt * 16 + fr] = f2bf(v);
                pl = fmaf(v, al4[nt], pl);
                pr = fmaf(v, ar4[nt], pr);
            }
            #pragma unroll
            for (int o = 1; o < 16; o <<= 1) {
                pl += __shfl_xor(pl, o, 64);
                pr += __shfl_xor(pr, o, 64);
            }
            if (ok && fr == 0) {
                el[(size_t)row * NHEAD + wid] = pl;
                er[(size_t)row * NHEAD + wid] = pr;
            }
        }
    }
}

// ---------------- online-softmax aggregate over bf16 feats ----------------
// outF != nullptr: f32 out (final). Else hi/lo bf16 split (hidden).
__global__ __launch_bounds__(256) void agg_kernel3(const ushort* __restrict__ featB,
                                                   const float* __restrict__ el,
                                                   const float* __restrict__ er,
                                                   const int* __restrict__ offs,
                                                   const int* __restrict__ csr_src,
                                                   const float* __restrict__ bias,
                                                   float* __restrict__ outF,
                                                   ushort* __restrict__ outH,
                                                   ushort* __restrict__ outL,
                                                   int act, int n) {
    int node = blockIdx.x * 4 + (threadIdx.x >> 6);
    if (node >= n) return;
    int lane = threadIdx.x & 63;
    int h = lane >> 4;
    int j16 = lane & 15;
    int f = lane * 4;
    int start = offs[node];
    int deg = offs[node + 1] - start;
    float erh = er[node * NHEAD + h];

    float m = -1e30f, ssum = 0.f;
    float acc0 = 0.f, acc1 = 0.f, acc2 = 0.f, acc3 = 0.f;
    int sidx = (j16 < deg) ? csr_src[start + j16] : 0;

    for (int p0 = 0; p0 < deg; p0 += 16) {
        int pn = p0 + 16 + j16;
        int sidx_nx = (pn < deg) ? csr_src[start + pn] : 0;   // prefetch next chunk
        float e = -1e30f;
        if (p0 + j16 < deg) {
            float t = el[sidx * NHEAD + h] + erh;
            e = (t > 0.f) ? t : 0.2f * t;
        }
        float cm = e;
        #pragma unroll
        for (int o = 1; o < 16; o <<= 1) cm = fmaxf(cm, __shfl_xor(cm, o, 64));
        float newm = fmaxf(m, cm);
        float sc = __expf(m - newm);
        m = newm;
        ssum *= sc; acc0 *= sc; acc1 *= sc; acc2 *= sc; acc3 *= sc;
        float w = __expf(e - m);   // masked lanes: exp(-inf) = 0
        ssum += w;
        int cnt = min(16, deg - p0);
        if (cnt == 16) {
            #pragma unroll
            for (int j = 0; j < 16; ++j) {
                float wj = __shfl(w, j, 16);
                int sj = __shfl(sidx, j, 16);
                ushort4 v = *(const ushort4*)(featB + (size_t)sj * FEAT + f);
                acc0 = fmaf(wj, bf2f(v.x), acc0);
                acc1 = fmaf(wj, bf2f(v.y), acc1);
                acc2 = fmaf(wj, bf2f(v.z), acc2);
                acc3 = fmaf(wj, bf2f(v.w), acc3);
            }
        } else {
            for (int j = 0; j < cnt; ++j) {
                float wj = __shfl(w, j, 16);
                int sj = __shfl(sidx, j, 16);
                ushort4 v = *(const ushort4*)(featB + (size_t)sj * FEAT + f);
                acc0 = fmaf(wj, bf2f(v.x), acc0);
                acc1 = fmaf(wj, bf2f(v.y), acc1);
                acc2 = fmaf(wj, bf2f(v.z), acc2);
                acc3 = fmaf(wj, bf2f(v.w), acc3);
            }
        }
        sidx = sidx_nx;
    }
    float st = ssum;
    #pragma unroll
    for (int o = 1; o < 16; o <<= 1) st += __shfl_xor(st, o, 64);
    float inv = 1.f / fmaxf(st, 1e-9f);
    float4 b4 = *(const float4*)(bias + f);
    float o0 = fmaf(acc0, inv, b4.x);
    float o1 = fmaf(acc1, inv, b4.y);
    float o2 = fmaf(acc2, inv, b4.z);
    float o3 = fmaf(acc3, inv, b4.w);
    if (act) {
        o0 = (o0 > 0.f) ? o0 : expm1f(o0);
        o1 = (o1 > 0.f) ? o1 : expm1f(o1);
        o2 = (o2 > 0.f) ? o2 : expm1f(o2);
        o3 = (o3 > 0.f) ? o3 : expm1f(o3);
    }
    if (outF) {
        *((float4*)(outF + (size_t)node * FEAT + f)) = make_float4(o0, o1, o2, o3);
    } else {
        ushort4 hh, ll;
        hh.x = f2bf(o0); ll.x = f2bf(o0 - bf2f(hh.x));
        hh.y = f2bf(o1); ll.y = f2bf(o1 - bf2f(hh.y));
        hh.z = f2bf(o2); ll.z = f2bf(o2 - bf2f(hh.z));
        hh.w = f2bf(o3); ll.w = f2bf(o3 - bf2f(hh.w));
        *(ushort4*)(outH + (size_t)node * FEAT + f) = hh;
        *(ushort4*)(outL + (size_t)node * FEAT + f) = ll;
    }
}

// ---------------------------------------------------------------------------
extern "C" void kernel_launch(void* const* d_in, const int* in_sizes, int n_in,
                              void* d_out, int out_size, void* d_ws, size_t ws_size,
                              hipStream_t stream) {
    const float* features = (const float*)d_in[0];
    const int*   src      = (const int*)d_in[1];
    const int*   dst      = (const int*)d_in[2];
    const int N = in_sizes[0] / FEAT;
    const int E = in_sizes[1];

    // ---- carve workspace ----
    char* ws = (char*)d_ws;
    size_t off = 0;
    auto carve = [&](size_t bytes) -> void* {
        void* p = ws + off;
        off = (off + bytes + 255) & ~(size_t)255;
        return p;
    };
    int*    deg     = (int*)carve((size_t)N * 4);
    int*    offs    = (int*)carve((size_t)(N + 1) * 4);
    int*    cursor  = (int*)carve((size_t)N * 4);
    int*    bsums   = (int*)carve(4096);
    int*    csr_src = (int*)carve((size_t)E * 4);
    float*  el      = (float*)carve((size_t)N * NHEAD * 4);
    float*  er      = (float*)carve((size_t)N * NHEAD * 4);
    ushort* featB   = (ushort*)carve((size_t)N * FEAT * 2);
    ushort* inAh    = (ushort*)carve((size_t)N * FEAT * 2);
    ushort* inAl    = (ushort*)carve((size_t)N * FEAT * 2);
    ushort* Wh[3], *Wl[3];
    for (int i = 0; i < 3; ++i) {
        Wh[i] = (ushort*)carve((size_t)FEAT * FEAT * 2);
        Wl[i] = (ushort*)carve((size_t)FEAT * FEAT * 2);
    }

    const int nbE = (E + 255) / 256;
    const int nbN = (N + 255) / 256;

    // ---- CSR build + W prep + feature split ----
    hipMemsetAsync(deg, 0, (size_t)N * 4, stream);
    hist_kernel<<<nbE, 256, 0, stream>>>(dst, deg, E);
    scan_block<<<nbN, 256, 0, stream>>>(deg, offs, bsums, N);
    scan_sums<<<1, 256, 0, stream>>>(bsums, nbN);
    scan_add<<<nbN, 256, 0, stream>>>(offs, cursor, bsums, N, E);
    scatter_kernel<<<nbE, 256, 0, stream>>>(src, dst, cursor, csr_src, E);
    wprep_kernel<<<FEAT, FEAT, 0, stream>>>((const float*)d_in[3],  Wh[0], Wl[0]);
    wprep_kernel<<<FEAT, FEAT, 0, stream>>>((const float*)d_in[7],  Wh[1], Wl[1]);
    wprep_kernel<<<FEAT, FEAT, 0, stream>>>((const float*)d_in[11], Wh[2], Wl[2]);
    const int total8 = N * FEAT / 8;
    fsplit_kernel<<<(total8 + 255) / 256, 256, 0, stream>>>(features, inAh, inAl, total8);

    const int gemmBlocks = (N + GBM - 1) / GBM;
    const int nodeBlocks = (N + 3) / 4;

    // ---- layer 1 ----
    gemm_fused<<<gemmBlocks, 256, 0, stream>>>(inAh, inAl, Wh[0], Wl[0],
                                               (const float*)d_in[4], (const float*)d_in[5],
                                               featB, el, er, N);
    agg_kernel3<<<nodeBlocks, 256, 0, stream>>>(featB, el, er, offs, csr_src,
                                                (const float*)d_in[6],
                                                (float*)nullptr, inAh, inAl, 1, N);
    // ---- layer 2 ----
    gemm_fused<<<gemmBlocks, 256, 0, stream>>>(inAh, inAl, Wh[1], Wl[1],
                                               (const float*)d_in[8], (const float*)d_in[9],
                                               featB, el, er, N);
    agg_kernel3<<<nodeBlocks, 256, 0, stream>>>(featB, el, er, offs, csr_src,
                                                (const float*)d_in[10],
                                                (float*)nullptr, inAh, inAl, 1, N);
    // ---- layer 3 ----
    gemm_fused<<<gemmBlocks, 256, 0, stream>>>(inAh, inAl, Wh[2], Wl[2],
                                               (const float*)d_in[12], (const float*)d_in[13],
                                               featB, el, er, N);
    agg_kernel3<<<nodeBlocks, 256, 0, stream>>>(featB, el, er, offs, csr_src,
                                                (const float*)d_in[14],
                                                (float*)d_out, (ushort*)nullptr, (ushort*)nullptr, 0, N);
}

// Round 12
// 511.163 us; speedup vs baseline: 1.1010x; 1.0133x over previous
//
#include <hip/hip_runtime.h>
#include <hip/hip_bf16.h>
#include <cstdint>

// ---------------------------------------------------------------------------
// GAT 3-layer forward. N=50000, E=800000, H=4, D=64 (FEAT = H*D = 256 = F_IN).
// R12 = R11 + correctness fix: agg_kernel4 now reduces the even/odd edge-parity
// partial accumulators across lane^32 before normalization (R11 raced two
// half-sums onto the same address), and gates the store on eh==0.
// ---------------------------------------------------------------------------

#define FEAT 256
#define NHEAD 4

typedef short short8 __attribute__((ext_vector_type(8)));
typedef float f32x4 __attribute__((ext_vector_type(4)));

__device__ __forceinline__ ushort f2bf(float v) {
    uint u = __float_as_uint(v);
    uint r = (u + 0x7fffu + ((u >> 16) & 1u)) >> 16;
    return (ushort)r;
}
__device__ __forceinline__ float bf2f(ushort h) {
    return __uint_as_float(((uint)h) << 16);
}

// ---------------- CSR build ----------------
__global__ void hist_kernel(const int* __restrict__ dst, int* __restrict__ deg, int E) {
    int e = blockIdx.x * 256 + threadIdx.x;
    if (e < E) atomicAdd(&deg[dst[e]], 1);
}

__global__ void scan_block(const int* __restrict__ deg, int* __restrict__ offs,
                           int* __restrict__ bsums, int n) {
    __shared__ int s[256];
    int i = blockIdx.x * 256 + threadIdx.x;
    int v = (i < n) ? deg[i] : 0;
    s[threadIdx.x] = v; __syncthreads();
    #pragma unroll
    for (int off = 1; off < 256; off <<= 1) {
        int t = (threadIdx.x >= off) ? s[threadIdx.x - off] : 0;
        __syncthreads();
        s[threadIdx.x] += t;
        __syncthreads();
    }
    if (i < n) offs[i] = s[threadIdx.x] - v;
    if (threadIdx.x == 255) bsums[blockIdx.x] = s[255];
}

__global__ void scan_sums(int* __restrict__ bsums, int nb) {
    __shared__ int s[256];
    int v = (threadIdx.x < nb) ? bsums[threadIdx.x] : 0;
    s[threadIdx.x] = v; __syncthreads();
    #pragma unroll
    for (int off = 1; off < 256; off <<= 1) {
        int t = (threadIdx.x >= off) ? s[threadIdx.x - off] : 0;
        __syncthreads();
        s[threadIdx.x] += t;
        __syncthreads();
    }
    if (threadIdx.x < nb) bsums[threadIdx.x] = s[threadIdx.x] - v;
}

__global__ void scan_add(int* __restrict__ offs, int* __restrict__ cursor,
                         const int* __restrict__ bsums, int n, int total) {
    int i = blockIdx.x * 256 + threadIdx.x;
    if (i < n) {
        int o = offs[i] + bsums[i >> 8];
        offs[i] = o;
        cursor[i] = o;
    }
    if (i == 0) offs[n] = total;
}

__global__ void scatter_kernel(const int* __restrict__ src, const int* __restrict__ dst,
                               int* __restrict__ cursor, int* __restrict__ csr_src, int E) {
    int e = blockIdx.x * 256 + threadIdx.x;
    if (e < E) {
        int d = dst[e];
        int pos = atomicAdd(&cursor[d], 1);
        csr_src[pos] = src[e];
    }
}

// ---------------- W prep: split f32 W[k][n] -> bf16 hi/lo, transposed [n][k] ----
__global__ void wprep_kernel(const float* __restrict__ W,
                             ushort* __restrict__ Wh, ushort* __restrict__ Wl) {
    int n = blockIdx.x;
    int k = threadIdx.x;
    float v = W[(size_t)k * FEAT + n];
    ushort h = f2bf(v);
    float r = v - bf2f(h);
    Wh[(size_t)n * FEAT + k] = h;
    Wl[(size_t)n * FEAT + k] = f2bf(r);
}

// ---------------- fsplit: f32 row-major -> hi/lo bf16 (elementwise) ----------------
__global__ void fsplit_kernel(const float* __restrict__ A, ushort* __restrict__ Ah,
                              ushort* __restrict__ Al, int total8) {
    int i = blockIdx.x * 256 + threadIdx.x;
    if (i >= total8) return;
    const float4* p = (const float4*)(A + (size_t)i * 8);
    float4 a = p[0], b = p[1];
    float v[8] = {a.x, a.y, a.z, a.w, b.x, b.y, b.z, b.w};
    ushort hi[8], lo[8];
    #pragma unroll
    for (int t = 0; t < 8; ++t) {
        hi[t] = f2bf(v[t]);
        lo[t] = f2bf(v[t] - bf2f(hi[t]));
    }
    *(short8*)(Ah + (size_t)i * 8) = *(short8*)hi;
    *(short8*)(Al + (size_t)i * 8) = *(short8*)lo;
}

// ---------------- fused GEMM 64x256: A in LDS, B direct global->reg ----------------
// feat = (Ah+Al) @ (Wh+Wl); featB = bf16(feat); el/er = head-dot with al/ar.
// 4 waves; wave w owns cols [64w, 64w+64) == head w.
#define GBM 64
#define GBK 32
#define LDK 40   // padded K stride in ushorts (80 B rows): 2-way bank alias only

__global__ __launch_bounds__(256) void gemm_fused(const ushort* __restrict__ Ahg,
                                                  const ushort* __restrict__ Alg,
                                                  const ushort* __restrict__ Whg,
                                                  const ushort* __restrict__ Wlg,
                                                  const float* __restrict__ alv,
                                                  const float* __restrict__ arv,
                                                  ushort* __restrict__ featB,
                                                  float* __restrict__ el,
                                                  float* __restrict__ er, int M) {
    __shared__ ushort Ah[GBM][LDK];
    __shared__ ushort Al[GBM][LDK];

    const int tid  = threadIdx.x;
    const int lane = tid & 63;
    const int wid  = tid >> 6;          // wave == head == col block
    const int row0 = blockIdx.x * GBM;

    const int arow = tid >> 2;          // A stage row 0..63
    const int achk = (tid & 3) * 8;     // A stage k chunk (ushort offset)

    const int fr = lane & 15;
    const int fk = (lane >> 4) * 8;
    const int q  = lane >> 4;

    f32x4 acc[4][4];
    #pragma unroll
    for (int i = 0; i < 4; ++i)
        #pragma unroll
        for (int j = 0; j < 4; ++j) {
            f32x4 z = {0.f, 0.f, 0.f, 0.f};
            acc[i][j] = z;
        }

    const short8 z8 = {0, 0, 0, 0, 0, 0, 0, 0};

    for (int k0 = 0; k0 < FEAT; k0 += GBK) {
        // A global loads (staged to LDS)
        short8 a_h, a_l;
        if (row0 + arow < M) {
            a_h = *(const short8*)(Ahg + (size_t)(row0 + arow) * FEAT + k0 + achk);
            a_l = *(const short8*)(Alg + (size_t)(row0 + arow) * FEAT + k0 + achk);
        } else {
            a_h = z8; a_l = z8;
        }
        // B fragments straight from global (W is L2-resident, [n][k] layout)
        short8 bfh[4], bfl[4];
        #pragma unroll
        for (int nt = 0; nt < 4; ++nt) {
            size_t boff = (size_t)(wid * 64 + nt * 16 + fr) * FEAT + k0 + fk;
            bfh[nt] = *(const short8*)(Whg + boff);
            bfl[nt] = *(const short8*)(Wlg + boff);
        }

        __syncthreads();   // previous iteration's LDS reads done
        *(short8*)&Ah[arow][achk] = a_h;
        *(short8*)&Al[arow][achk] = a_l;
        __syncthreads();

        #pragma unroll
        for (int mt = 0; mt < 4; ++mt) {
            short8 afh = *(const short8*)&Ah[mt * 16 + fr][fk];
            short8 afl = *(const short8*)&Al[mt * 16 + fr][fk];
            #pragma unroll
            for (int nt = 0; nt < 4; ++nt) {
                acc[mt][nt] = __builtin_amdgcn_mfma_f32_16x16x32_bf16(
                    afh, bfh[nt], acc[mt][nt], 0, 0, 0);
                acc[mt][nt] = __builtin_amdgcn_mfma_f32_16x16x32_bf16(
                    afh, bfl[nt], acc[mt][nt], 0, 0, 0);
                acc[mt][nt] = __builtin_amdgcn_mfma_f32_16x16x32_bf16(
                    afl, bfh[nt], acc[mt][nt], 0, 0, 0);
            }
        }
    }

    // ---- epilogue: featB (bf16) + el/er for this wave's head ----
    float al4[4], ar4[4];
    #pragma unroll
    for (int nt = 0; nt < 4; ++nt) {
        al4[nt] = alv[wid * 64 + nt * 16 + fr];
        ar4[nt] = arv[wid * 64 + nt * 16 + fr];
    }
    #pragma unroll
    for (int mt = 0; mt < 4; ++mt) {
        #pragma unroll
        for (int r = 0; r < 4; ++r) {
            int row = row0 + mt * 16 + q * 4 + r;
            bool ok = row < M;
            float pl = 0.f, pr = 0.f;
            #pragma unroll
            for (int nt = 0; nt < 4; ++nt) {
                float v = acc[mt][nt][r];
                if (ok) featB[(size_t)row * FEAT + wid * 64 + nt * 16 + fr] = f2bf(v);
                pl = fmaf(v, al4[nt], pl);
                pr = fmaf(v, ar4[nt], pr);
            }
            #pragma unroll
            for (int o = 1; o < 16; o <<= 1) {   // reduce within 16-lane group
                pl += __shfl_xor(pl, o, 64);
                pr += __shfl_xor(pr, o, 64);
            }
            if (ok && fr == 0) {
                el[(size_t)row * NHEAD + wid] = pl;
                er[(size_t)row * NHEAD + wid] = pr;
            }
        }
    }
}

// ---------------- online-softmax aggregate: 2 waves/node, 2 edges in flight ----------
// Wave wv of a node owns head pair {2wv, 2wv+1} = feats [128wv, 128wv+128).
// e-phase: lane = 32*eh + j32 computes e for edge-slot j32, head 2wv+eh (chunk=32).
// gather-phase: half-wave eh handles edges j0 = 2i+eh; lane loads 4 feats (8B)
// at fbase = 128wv + (lane&31)*4; accumulators belong to head 2wv+((lane&31)>>4).
// Epilogue: partials of the two edge parities live at lane and lane^32 -> XOR-sum,
// then lanes with eh==0 store. outF: f32 (final). Else hi/lo bf16 split (hidden).
__global__ __launch_bounds__(256) void agg_kernel4(const ushort* __restrict__ featB,
                                                   const float* __restrict__ el,
                                                   const float* __restrict__ er,
                                                   const int* __restrict__ offs,
                                                   const int* __restrict__ csr_src,
                                                   const float* __restrict__ bias,
                                                   float* __restrict__ outF,
                                                   ushort* __restrict__ outH,
                                                   ushort* __restrict__ outL,
                                                   int act, int n) {
    int node = blockIdx.x * 2 + (threadIdx.x >> 7);
    if (node >= n) return;
    int lane = threadIdx.x & 63;
    int wv   = (threadIdx.x >> 6) & 1;    // head-pair index
    int j32  = lane & 31;                 // e-role: edge slot / gather: feat-lane
    int eh   = lane >> 5;                 // e-role: head-of-pair / gather: edge parity
    int fbase = wv * 128 + j32 * 4;       // 4 contiguous feats
    int acch  = j32 >> 4;                 // head-of-pair my accumulators belong to
    int srcbase = acch << 5;              // first lane of my acc-head's e-role half
    int myh_e = wv * 2 + eh;              // e-role head
    int start = offs[node];
    int deg = offs[node + 1] - start;
    float erh = er[node * NHEAD + myh_e];

    float m = -1e30f, ssum = 0.f;
    float a0 = 0.f, a1 = 0.f, a2 = 0.f, a3 = 0.f;
    int sidx = (j32 < deg) ? csr_src[start + j32] : 0;

    for (int p0 = 0; p0 < deg; p0 += 32) {
        int pn = p0 + 32 + j32;
        int sidx_nx = (pn < deg) ? csr_src[start + pn] : 0;   // prefetch next chunk
        float e = -1e30f;
        if (p0 + j32 < deg) {
            float t = el[sidx * NHEAD + myh_e] + erh;
            e = (t > 0.f) ? t : 0.2f * t;
        }
        float cm = e;
        #pragma unroll
        for (int o = 1; o < 32; o <<= 1) cm = fmaxf(cm, __shfl_xor(cm, o, 32));
        float newm = fmaxf(m, cm);
        float sc = __expf(m - newm);      // uniform within my e-role half
        m = newm;
        float sc_acc = __shfl(sc, srcbase, 64);   // sc of my ACC-head
        ssum *= sc;                                // ssum is e-role
        a0 *= sc_acc; a1 *= sc_acc; a2 *= sc_acc; a3 *= sc_acc;
        float w = __expf(e - m);          // masked slots: exp(-inf) = 0
        ssum += w;
        int cnt = min(32, deg - p0);
        int iters = (cnt + 1) >> 1;
        int wsrc = srcbase + eh;          // w-source lane = srcbase + j0, j0 = 2i+eh
        for (int i = 0; i < iters; ++i) {
            int j0 = 2 * i + eh;
            int sj = __shfl(sidx, j0, 32);            // edge j0's src node
            float wj = __shfl(w, wsrc + 2 * i, 64);   // w(acc-head, edge j0); 0 if j0>=cnt
            ushort4 v = *(const ushort4*)(featB + (size_t)sj * FEAT + fbase);
            a0 = fmaf(wj, bf2f(v.x), a0);
            a1 = fmaf(wj, bf2f(v.y), a1);
            a2 = fmaf(wj, bf2f(v.z), a2);
            a3 = fmaf(wj, bf2f(v.w), a3);
        }
        sidx = sidx_nx;
    }
    // ---- combine even/odd edge-parity partials (lane ^ 32 holds the other half) ----
    a0 += __shfl_xor(a0, 32, 64);
    a1 += __shfl_xor(a1, 32, 64);
    a2 += __shfl_xor(a2, 32, 64);
    a3 += __shfl_xor(a3, 32, 64);

    float st = ssum;
    #pragma unroll
    for (int o = 1; o < 32; o <<= 1) st += __shfl_xor(st, o, 32);
    st = __shfl(st, srcbase, 64);         // total for my ACC-head
    if (eh == 0) {                        // lanes 0..31 cover all 128 feats
        float inv = 1.f / fmaxf(st, 1e-9f);
        float4 b4 = *(const float4*)(bias + fbase);
        float o0 = fmaf(a0, inv, b4.x);
        float o1 = fmaf(a1, inv, b4.y);
        float o2 = fmaf(a2, inv, b4.z);
        float o3 = fmaf(a3, inv, b4.w);
        if (act) {
            o0 = (o0 > 0.f) ? o0 : expm1f(o0);
            o1 = (o1 > 0.f) ? o1 : expm1f(o1);
            o2 = (o2 > 0.f) ? o2 : expm1f(o2);
            o3 = (o3 > 0.f) ? o3 : expm1f(o3);
        }
        if (outF) {
            *((float4*)(outF + (size_t)node * FEAT + fbase)) = make_float4(o0, o1, o2, o3);
        } else {
            ushort4 hh, ll;
            hh.x = f2bf(o0); ll.x = f2bf(o0 - bf2f(hh.x));
            hh.y = f2bf(o1); ll.y = f2bf(o1 - bf2f(hh.y));
            hh.z = f2bf(o2); ll.z = f2bf(o2 - bf2f(hh.z));
            hh.w = f2bf(o3); ll.w = f2bf(o3 - bf2f(hh.w));
            *(ushort4*)(outH + (size_t)node * FEAT + fbase) = hh;
            *(ushort4*)(outL + (size_t)node * FEAT + fbase) = ll;
        }
    }
}

// ---------------------------------------------------------------------------
extern "C" void kernel_launch(void* const* d_in, const int* in_sizes, int n_in,
                              void* d_out, int out_size, void* d_ws, size_t ws_size,
                              hipStream_t stream) {
    const float* features = (const float*)d_in[0];
    const int*   src      = (const int*)d_in[1];
    const int*   dst      = (const int*)d_in[2];
    const int N = in_sizes[0] / FEAT;
    const int E = in_sizes[1];

    // ---- carve workspace ----
    char* ws = (char*)d_ws;
    size_t off = 0;
    auto carve = [&](size_t bytes) -> void* {
        void* p = ws + off;
        off = (off + bytes + 255) & ~(size_t)255;
        return p;
    };
    int*    deg     = (int*)carve((size_t)N * 4);
    int*    offs    = (int*)carve((size_t)(N + 1) * 4);
    int*    cursor  = (int*)carve((size_t)N * 4);
    int*    bsums   = (int*)carve(4096);
    int*    csr_src = (int*)carve((size_t)E * 4);
    float*  el      = (float*)carve((size_t)N * NHEAD * 4);
    float*  er      = (float*)carve((size_t)N * NHEAD * 4);
    ushort* featB   = (ushort*)carve((size_t)N * FEAT * 2);
    ushort* inAh    = (ushort*)carve((size_t)N * FEAT * 2);
    ushort* inAl    = (ushort*)carve((size_t)N * FEAT * 2);
    ushort* Wh[3], *Wl[3];
    for (int i = 0; i < 3; ++i) {
        Wh[i] = (ushort*)carve((size_t)FEAT * FEAT * 2);
        Wl[i] = (ushort*)carve((size_t)FEAT * FEAT * 2);
    }

    const int nbE = (E + 255) / 256;
    const int nbN = (N + 255) / 256;

    // ---- CSR build + W prep + feature split ----
    hipMemsetAsync(deg, 0, (size_t)N * 4, stream);
    hist_kernel<<<nbE, 256, 0, stream>>>(dst, deg, E);
    scan_block<<<nbN, 256, 0, stream>>>(deg, offs, bsums, N);
    scan_sums<<<1, 256, 0, stream>>>(bsums, nbN);
    scan_add<<<nbN, 256, 0, stream>>>(offs, cursor, bsums, N, E);
    scatter_kernel<<<nbE, 256, 0, stream>>>(src, dst, cursor, csr_src, E);
    wprep_kernel<<<FEAT, FEAT, 0, stream>>>((const float*)d_in[3],  Wh[0], Wl[0]);
    wprep_kernel<<<FEAT, FEAT, 0, stream>>>((const float*)d_in[7],  Wh[1], Wl[1]);
    wprep_kernel<<<FEAT, FEAT, 0, stream>>>((const float*)d_in[11], Wh[2], Wl[2]);
    const int total8 = N * FEAT / 8;
    fsplit_kernel<<<(total8 + 255) / 256, 256, 0, stream>>>(features, inAh, inAl, total8);

    const int gemmBlocks = (N + GBM - 1) / GBM;
    const int aggBlocks  = (N + 1) / 2;

    // ---- layer 1 ----
    gemm_fused<<<gemmBlocks, 256, 0, stream>>>(inAh, inAl, Wh[0], Wl[0],
                                               (const float*)d_in[4], (const float*)d_in[5],
                                               featB, el, er, N);
    agg_kernel4<<<aggBlocks, 256, 0, stream>>>(featB, el, er, offs, csr_src,
                                               (const float*)d_in[6],
                                               (float*)nullptr, inAh, inAl, 1, N);
    // ---- layer 2 ----
    gemm_fused<<<gemmBlocks, 256, 0, stream>>>(inAh, inAl, Wh[1], Wl[1],
                                               (const float*)d_in[8], (const float*)d_in[9],
                                               featB, el, er, N);
    agg_kernel4<<<aggBlocks, 256, 0, stream>>>(featB, el, er, offs, csr_src,
                                               (const float*)d_in[10],
                                               (float*)nullptr, inAh, inAl, 1, N);
    // ---- layer 3 ----
    gemm_fused<<<gemmBlocks, 256, 0, stream>>>(inAh, inAl, Wh[2], Wl[2],
                                               (const float*)d_in[12], (const float*)d_in[13],
                                               featB, el, er, N);
    agg_kernel4<<<aggBlocks, 256, 0, stream>>>(featB, el, er, offs, csr_src,
                                               (const float*)d_in[14],
                                               (float*)d_out, (ushort*)nullptr, (ushort*)nullptr, 0, N);
}

// Round 14
// 489.975 us; speedup vs baseline: 1.1486x; 1.0432x over previous
//
#include <hip/hip_runtime.h>
#include <hip/hip_bf16.h>
#include <cstdint>

// ---------------------------------------------------------------------------
// GAT 3-layer forward. N=50000, E=800000, H=4, D=64 (FEAT = H*D = 256 = F_IN).
// R13: (1) agg reverted to R10's proven 1-wave/node structure (R12's 2-wave
//      role transport was VALU/shuffle-bound: 73% VALUBusy, 2M bank conflicts);
//      (2) GEMM keeps B-direct-from-global and adds double-buffered A staging
//      (one barrier per k-iter, A/B loads hoisted above the barrier);
//      (3) 3x wprep fused into one dispatch.
// ---------------------------------------------------------------------------

#define FEAT 256
#define NHEAD 4

typedef short short8 __attribute__((ext_vector_type(8)));
typedef float f32x4 __attribute__((ext_vector_type(4)));

__device__ __forceinline__ ushort f2bf(float v) {
    uint u = __float_as_uint(v);
    uint r = (u + 0x7fffu + ((u >> 16) & 1u)) >> 16;
    return (ushort)r;
}
__device__ __forceinline__ float bf2f(ushort h) {
    return __uint_as_float(((uint)h) << 16);
}

// ---------------- CSR build ----------------
__global__ void hist_kernel(const int* __restrict__ dst, int* __restrict__ deg, int E) {
    int e = blockIdx.x * 256 + threadIdx.x;
    if (e < E) atomicAdd(&deg[dst[e]], 1);
}

__global__ void scan_block(const int* __restrict__ deg, int* __restrict__ offs,
                           int* __restrict__ bsums, int n) {
    __shared__ int s[256];
    int i = blockIdx.x * 256 + threadIdx.x;
    int v = (i < n) ? deg[i] : 0;
    s[threadIdx.x] = v; __syncthreads();
    #pragma unroll
    for (int off = 1; off < 256; off <<= 1) {
        int t = (threadIdx.x >= off) ? s[threadIdx.x - off] : 0;
        __syncthreads();
        s[threadIdx.x] += t;
        __syncthreads();
    }
    if (i < n) offs[i] = s[threadIdx.x] - v;
    if (threadIdx.x == 255) bsums[blockIdx.x] = s[255];
}

__global__ void scan_sums(int* __restrict__ bsums, int nb) {
    __shared__ int s[256];
    int v = (threadIdx.x < nb) ? bsums[threadIdx.x] : 0;
    s[threadIdx.x] = v; __syncthreads();
    #pragma unroll
    for (int off = 1; off < 256; off <<= 1) {
        int t = (threadIdx.x >= off) ? s[threadIdx.x - off] : 0;
        __syncthreads();
        s[threadIdx.x] += t;
        __syncthreads();
    }
    if (threadIdx.x < nb) bsums[threadIdx.x] = s[threadIdx.x] - v;
}

__global__ void scan_add(int* __restrict__ offs, int* __restrict__ cursor,
                         const int* __restrict__ bsums, int n, int total) {
    int i = blockIdx.x * 256 + threadIdx.x;
    if (i < n) {
        int o = offs[i] + bsums[i >> 8];
        offs[i] = o;
        cursor[i] = o;
    }
    if (i == 0) offs[n] = total;
}

__global__ void scatter_kernel(const int* __restrict__ src, const int* __restrict__ dst,
                               int* __restrict__ cursor, int* __restrict__ csr_src, int E) {
    int e = blockIdx.x * 256 + threadIdx.x;
    if (e < E) {
        int d = dst[e];
        int pos = atomicAdd(&cursor[d], 1);
        csr_src[pos] = src[e];
    }
}

// ---------------- W prep (all 3 layers in one dispatch) ----------------
// Split f32 W[k][n] -> bf16 hi/lo, transposed [n][k]. blockIdx.y = layer.
__global__ void wprep3_kernel(const float* __restrict__ W0, const float* __restrict__ W1,
                              const float* __restrict__ W2,
                              ushort* __restrict__ Wh0, ushort* __restrict__ Wl0,
                              ushort* __restrict__ Wh1, ushort* __restrict__ Wl1,
                              ushort* __restrict__ Wh2, ushort* __restrict__ Wl2) {
    const float* W = (blockIdx.y == 0) ? W0 : (blockIdx.y == 1) ? W1 : W2;
    ushort* Wh = (blockIdx.y == 0) ? Wh0 : (blockIdx.y == 1) ? Wh1 : Wh2;
    ushort* Wl = (blockIdx.y == 0) ? Wl0 : (blockIdx.y == 1) ? Wl1 : Wl2;
    int n = blockIdx.x;
    int k = threadIdx.x;
    float v = W[(size_t)k * FEAT + n];
    ushort h = f2bf(v);
    float r = v - bf2f(h);
    Wh[(size_t)n * FEAT + k] = h;
    Wl[(size_t)n * FEAT + k] = f2bf(r);
}

// ---------------- fsplit: f32 row-major -> hi/lo bf16 (elementwise) ----------------
__global__ void fsplit_kernel(const float* __restrict__ A, ushort* __restrict__ Ah,
                              ushort* __restrict__ Al, int total8) {
    int i = blockIdx.x * 256 + threadIdx.x;
    if (i >= total8) return;
    const float4* p = (const float4*)(A + (size_t)i * 8);
    float4 a = p[0], b = p[1];
    float v[8] = {a.x, a.y, a.z, a.w, b.x, b.y, b.z, b.w};
    ushort hi[8], lo[8];
    #pragma unroll
    for (int t = 0; t < 8; ++t) {
        hi[t] = f2bf(v[t]);
        lo[t] = f2bf(v[t] - bf2f(hi[t]));
    }
    *(short8*)(Ah + (size_t)i * 8) = *(short8*)hi;
    *(short8*)(Al + (size_t)i * 8) = *(short8*)lo;
}

// ---------------- fused GEMM 64x256: A double-buffered in LDS, B global->reg ------
// feat = (Ah+Al) @ (Wh+Wl); featB = bf16(feat); el/er = head-dot with al/ar.
// 4 waves; wave w owns cols [64w, 64w+64) == head w. One barrier per k-iter.
#define GBM 64
#define GBK 32
#define LDK 40   // padded K stride in ushorts (80 B rows): 2-way bank alias only
#define NKIT (FEAT / GBK)   // 8

__global__ __launch_bounds__(256) void gemm_fused(const ushort* __restrict__ Ahg,
                                                  const ushort* __restrict__ Alg,
                                                  const ushort* __restrict__ Whg,
                                                  const ushort* __restrict__ Wlg,
                                                  const float* __restrict__ alv,
                                                  const float* __restrict__ arv,
                                                  ushort* __restrict__ featB,
                                                  float* __restrict__ el,
                                                  float* __restrict__ er, int M) {
    __shared__ ushort Ah[2][GBM][LDK];
    __shared__ ushort Al[2][GBM][LDK];

    const int tid  = threadIdx.x;
    const int lane = tid & 63;
    const int wid  = tid >> 6;          // wave == head == col block
    const int row0 = blockIdx.x * GBM;

    const int arow = tid >> 2;          // A stage row 0..63
    const int achk = (tid & 3) * 8;     // A stage k chunk (ushort offset)
    const bool aok = (row0 + arow) < M;
    const ushort* ApH = Ahg + (size_t)(row0 + arow) * FEAT + achk;
    const ushort* ApL = Alg + (size_t)(row0 + arow) * FEAT + achk;

    const int fr = lane & 15;
    const int fk = (lane >> 4) * 8;
    const int q  = lane >> 4;

    f32x4 acc[4][4];
    #pragma unroll
    for (int i = 0; i < 4; ++i)
        #pragma unroll
        for (int j = 0; j < 4; ++j) {
            f32x4 z = {0.f, 0.f, 0.f, 0.f};
            acc[i][j] = z;
        }

    const short8 z8 = {0, 0, 0, 0, 0, 0, 0, 0};

    // prologue: stage k-iter 0 into buffer 0
    {
        short8 a_h = aok ? *(const short8*)(ApH) : z8;
        short8 a_l = aok ? *(const short8*)(ApL) : z8;
        *(short8*)&Ah[0][arow][achk] = a_h;
        *(short8*)&Al[0][arow][achk] = a_l;
    }

    #pragma unroll
    for (int t = 0; t < NKIT; ++t) {
        const int cur = t & 1;
        const int k0 = t * GBK;
        // prefetch next A tile (regs) -- hides under this iter's MFMA
        short8 a_h = z8, a_l = z8;
        if (t + 1 < NKIT && aok) {
            a_h = *(const short8*)(ApH + k0 + GBK);
            a_l = *(const short8*)(ApL + k0 + GBK);
        }
        // B fragments straight from global (W is L2-resident, [n][k] layout)
        short8 bfh[4], bfl[4];
        #pragma unroll
        for (int nt = 0; nt < 4; ++nt) {
            size_t boff = (size_t)(wid * 64 + nt * 16 + fr) * FEAT + k0 + fk;
            bfh[nt] = *(const short8*)(Whg + boff);
            bfl[nt] = *(const short8*)(Wlg + boff);
        }

        __syncthreads();   // buf[cur] writes visible; prior reads of buf[cur^1] done

        #pragma unroll
        for (int mt = 0; mt < 4; ++mt) {
            short8 afh = *(const short8*)&Ah[cur][mt * 16 + fr][fk];
            short8 afl = *(const short8*)&Al[cur][mt * 16 + fr][fk];
            #pragma unroll
            for (int nt = 0; nt < 4; ++nt) {
                acc[mt][nt] = __builtin_amdgcn_mfma_f32_16x16x32_bf16(
                    afh, bfh[nt], acc[mt][nt], 0, 0, 0);
                acc[mt][nt] = __builtin_amdgcn_mfma_f32_16x16x32_bf16(
                    afh, bfl[nt], acc[mt][nt], 0, 0, 0);
                acc[mt][nt] = __builtin_amdgcn_mfma_f32_16x16x32_bf16(
                    afl, bfh[nt], acc[mt][nt], 0, 0, 0);
            }
        }
        if (t + 1 < NKIT) {
            *(short8*)&Ah[cur ^ 1][arow][achk] = a_h;
            *(short8*)&Al[cur ^ 1][arow][achk] = a_l;
        }
    }

    // ---- epilogue: featB (bf16) + el/er for this wave's head ----
    float al4[4], ar4[4];
    #pragma unroll
    for (int nt = 0; nt < 4; ++nt) {
        al4[nt] = alv[wid * 64 + nt * 16 + fr];
        ar4[nt] = arv[wid * 64 + nt * 16 + fr];
    }
    #pragma unroll
    for (int mt = 0; mt < 4; ++mt) {
        #pragma unroll
        for (int r = 0; r < 4; ++r) {
            int row = row0 + mt * 16 + q * 4 + r;
            bool ok = row < M;
            float pl = 0.f, pr = 0.f;
            #pragma unroll
            for (int nt = 0; nt < 4; ++nt) {
                float v = acc[mt][nt][r];
                if (ok) featB[(size_t)row * FEAT + wid * 64 + nt * 16 + fr] = f2bf(v);
                pl = fmaf(v, al4[nt], pl);
                pr = fmaf(v, ar4[nt], pr);
            }
            #pragma unroll
            for (int o = 1; o < 16; o <<= 1) {   // reduce within 16-lane group
                pl += __shfl_xor(pl, o, 64);
                pr += __shfl_xor(pr, o, 64);
            }
            if (ok && fr == 0) {
                el[(size_t)row * NHEAD + wid] = pl;
                er[(size_t)row * NHEAD + wid] = pr;
            }
        }
    }
}

// ---------------- online-softmax aggregate (R10 structure, proven 83 us) ----------
// One wave per node; 16-lane head groups; 16-edge chunks; bf16 gather.
// outF != nullptr: f32 out (final). Else hi/lo bf16 split (hidden).
__global__ __launch_bounds__(256) void agg_kernel3(const ushort* __restrict__ featB,
                                                   const float* __restrict__ el,
                                                   const float* __restrict__ er,
                                                   const int* __restrict__ offs,
                                                   const int* __restrict__ csr_src,
                                                   const float* __restrict__ bias,
                                                   float* __restrict__ outF,
                                                   ushort* __restrict__ outH,
                                                   ushort* __restrict__ outL,
                                                   int act, int n) {
    int node = blockIdx.x * 4 + (threadIdx.x >> 6);
    if (node >= n) return;
    int lane = threadIdx.x & 63;
    int h = lane >> 4;
    int j16 = lane & 15;
    int f = lane * 4;
    int start = offs[node];
    int deg = offs[node + 1] - start;
    float erh = er[node * NHEAD + h];

    float m = -1e30f, ssum = 0.f;
    float acc0 = 0.f, acc1 = 0.f, acc2 = 0.f, acc3 = 0.f;
    int sidx = (j16 < deg) ? csr_src[start + j16] : 0;

    for (int p0 = 0; p0 < deg; p0 += 16) {
        int pn = p0 + 16 + j16;
        int sidx_nx = (pn < deg) ? csr_src[start + pn] : 0;   // prefetch next chunk
        float e = -1e30f;
        if (p0 + j16 < deg) {
            float t = el[sidx * NHEAD + h] + erh;
            e = (t > 0.f) ? t : 0.2f * t;
        }
        float cm = e;
        #pragma unroll
        for (int o = 1; o < 16; o <<= 1) cm = fmaxf(cm, __shfl_xor(cm, o, 64));
        float newm = fmaxf(m, cm);
        float sc = __expf(m - newm);
        m = newm;
        ssum *= sc; acc0 *= sc; acc1 *= sc; acc2 *= sc; acc3 *= sc;
        float w = __expf(e - m);   // masked lanes: exp(-inf) = 0
        ssum += w;
        int cnt = min(16, deg - p0);
        if (cnt == 16) {
            #pragma unroll
            for (int j = 0; j < 16; ++j) {
                float wj = __shfl(w, j, 16);
                int sj = __shfl(sidx, j, 16);
                ushort4 v = *(const ushort4*)(featB + (size_t)sj * FEAT + f);
                acc0 = fmaf(wj, bf2f(v.x), acc0);
                acc1 = fmaf(wj, bf2f(v.y), acc1);
                acc2 = fmaf(wj, bf2f(v.z), acc2);
                acc3 = fmaf(wj, bf2f(v.w), acc3);
            }
        } else {
            for (int j = 0; j < cnt; ++j) {
                float wj = __shfl(w, j, 16);
                int sj = __shfl(sidx, j, 16);
                ushort4 v = *(const ushort4*)(featB + (size_t)sj * FEAT + f);
                acc0 = fmaf(wj, bf2f(v.x), acc0);
                acc1 = fmaf(wj, bf2f(v.y), acc1);
                acc2 = fmaf(wj, bf2f(v.z), acc2);
                acc3 = fmaf(wj, bf2f(v.w), acc3);
            }
        }
        sidx = sidx_nx;
    }
    float st = ssum;
    #pragma unroll
    for (int o = 1; o < 16; o <<= 1) st += __shfl_xor(st, o, 64);
    float inv = 1.f / fmaxf(st, 1e-9f);
    float4 b4 = *(const float4*)(bias + f);
    float o0 = fmaf(acc0, inv, b4.x);
    float o1 = fmaf(acc1, inv, b4.y);
    float o2 = fmaf(acc2, inv, b4.z);
    float o3 = fmaf(acc3, inv, b4.w);
    if (act) {
        o0 = (o0 > 0.f) ? o0 : expm1f(o0);
        o1 = (o1 > 0.f) ? o1 : expm1f(o1);
        o2 = (o2 > 0.f) ? o2 : expm1f(o2);
        o3 = (o3 > 0.f) ? o3 : expm1f(o3);
    }
    if (outF) {
        *((float4*)(outF + (size_t)node * FEAT + f)) = make_float4(o0, o1, o2, o3);
    } else {
        ushort4 hh, ll;
        hh.x = f2bf(o0); ll.x = f2bf(o0 - bf2f(hh.x));
        hh.y = f2bf(o1); ll.y = f2bf(o1 - bf2f(hh.y));
        hh.z = f2bf(o2); ll.z = f2bf(o2 - bf2f(hh.z));
        hh.w = f2bf(o3); ll.w = f2bf(o3 - bf2f(hh.w));
        *(ushort4*)(outH + (size_t)node * FEAT + f) = hh;
        *(ushort4*)(outL + (size_t)node * FEAT + f) = ll;
    }
}

// ---------------------------------------------------------------------------
extern "C" void kernel_launch(void* const* d_in, const int* in_sizes, int n_in,
                              void* d_out, int out_size, void* d_ws, size_t ws_size,
                              hipStream_t stream) {
    const float* features = (const float*)d_in[0];
    const int*   src      = (const int*)d_in[1];
    const int*   dst      = (const int*)d_in[2];
    const int N = in_sizes[0] / FEAT;
    const int E = in_sizes[1];

    // ---- carve workspace ----
    char* ws = (char*)d_ws;
    size_t off = 0;
    auto carve = [&](size_t bytes) -> void* {
        void* p = ws + off;
        off = (off + bytes + 255) & ~(size_t)255;
        return p;
    };
    int*    deg     = (int*)carve((size_t)N * 4);
    int*    offs    = (int*)carve((size_t)(N + 1) * 4);
    int*    cursor  = (int*)carve((size_t)N * 4);
    int*    bsums   = (int*)carve(4096);
    int*    csr_src = (int*)carve((size_t)E * 4);
    float*  el      = (float*)carve((size_t)N * NHEAD * 4);
    float*  er      = (float*)carve((size_t)N * NHEAD * 4);
    ushort* featB   = (ushort*)carve((size_t)N * FEAT * 2);
    ushort* inAh    = (ushort*)carve((size_t)N * FEAT * 2);
    ushort* inAl    = (ushort*)carve((size_t)N * FEAT * 2);
    ushort* Wh[3], *Wl[3];
    for (int i = 0; i < 3; ++i) {
        Wh[i] = (ushort*)carve((size_t)FEAT * FEAT * 2);
        Wl[i] = (ushort*)carve((size_t)FEAT * FEAT * 2);
    }

    const int nbE = (E + 255) / 256;
    const int nbN = (N + 255) / 256;

    // ---- CSR build + W prep + feature split ----
    hipMemsetAsync(deg, 0, (size_t)N * 4, stream);
    hist_kernel<<<nbE, 256, 0, stream>>>(dst, deg, E);
    scan_block<<<nbN, 256, 0, stream>>>(deg, offs, bsums, N);
    scan_sums<<<1, 256, 0, stream>>>(bsums, nbN);
    scan_add<<<nbN, 256, 0, stream>>>(offs, cursor, bsums, N, E);
    scatter_kernel<<<nbE, 256, 0, stream>>>(src, dst, cursor, csr_src, E);
    dim3 wgrid(FEAT, 3);
    wprep3_kernel<<<wgrid, FEAT, 0, stream>>>((const float*)d_in[3], (const float*)d_in[7],
                                              (const float*)d_in[11],
                                              Wh[0], Wl[0], Wh[1], Wl[1], Wh[2], Wl[2]);
    const int total8 = N * FEAT / 8;
    fsplit_kernel<<<(total8 + 255) / 256, 256, 0, stream>>>(features, inAh, inAl, total8);

    const int gemmBlocks = (N + GBM - 1) / GBM;
    const int nodeBlocks = (N + 3) / 4;

    // ---- layer 1 ----
    gemm_fused<<<gemmBlocks, 256, 0, stream>>>(inAh, inAl, Wh[0], Wl[0],
                                               (const float*)d_in[4], (const float*)d_in[5],
                                               featB, el, er, N);
    agg_kernel3<<<nodeBlocks, 256, 0, stream>>>(featB, el, er, offs, csr_src,
                                                (const float*)d_in[6],
                                                (float*)nullptr, inAh, inAl, 1, N);
    // ---- layer 2 ----
    gemm_fused<<<gemmBlocks, 256, 0, stream>>>(inAh, inAl, Wh[1], Wl[1],
                                               (const float*)d_in[8], (const float*)d_in[9],
                                               featB, el, er, N);
    agg_kernel3<<<nodeBlocks, 256, 0, stream>>>(featB, el, er, offs, csr_src,
                                                (const float*)d_in[10],
                                                (float*)nullptr, inAh, inAl, 1, N);
    // ---- layer 3 ----
    gemm_fused<<<gemmBlocks, 256, 0, stream>>>(inAh, inAl, Wh[2], Wl[2],
                                               (const float*)d_in[12], (const float*)d_in[13],
                                               featB, el, er, N);
    agg_kernel3<<<nodeBlocks, 256, 0, stream>>>(featB, el, er, offs, csr_src,
                                                (const float*)d_in[14],
                                                (float*)d_out, (ushort*)nullptr, (ushort*)nullptr, 0, N);
}

// Round 16
// 473.963 us; speedup vs baseline: 1.1874x; 1.0338x over previous
//
#include <hip/hip_runtime.h>
#include <hip/hip_bf16.h>
#include <cstdint>

// ---------------------------------------------------------------------------
// GAT 3-layer forward. N=50000, E=800000, H=4, D=64 (FEAT = H*D = 256 = F_IN).
// R15: (1) GEMM GBM 64->128: each block reuses the per-wave B (W columns)
//      across 128 rows -> W L2 traffic halves (R14 post-mortem: 400 MB/dispatch
//      dominated gemm's 65 us); (2) agg gather phase processes 2 edges per
//      16B-lane load (half-wave per edge, 8 feats/lane) -> half the gather
//      instructions and shuffles; cross-parity shfl_xor(32) combine at end.
// ---------------------------------------------------------------------------

#define FEAT 256
#define NHEAD 4

typedef short short8 __attribute__((ext_vector_type(8)));
typedef float f32x4 __attribute__((ext_vector_type(4)));

__device__ __forceinline__ ushort f2bf(float v) {
    uint u = __float_as_uint(v);
    uint r = (u + 0x7fffu + ((u >> 16) & 1u)) >> 16;
    return (ushort)r;
}
__device__ __forceinline__ float bf2f(ushort h) {
    return __uint_as_float(((uint)h) << 16);
}

// ---------------- CSR build ----------------
__global__ void hist_kernel(const int* __restrict__ dst, int* __restrict__ deg, int E) {
    int e = blockIdx.x * 256 + threadIdx.x;
    if (e < E) atomicAdd(&deg[dst[e]], 1);
}

__global__ void scan_block(const int* __restrict__ deg, int* __restrict__ offs,
                           int* __restrict__ bsums, int n) {
    __shared__ int s[256];
    int i = blockIdx.x * 256 + threadIdx.x;
    int v = (i < n) ? deg[i] : 0;
    s[threadIdx.x] = v; __syncthreads();
    #pragma unroll
    for (int off = 1; off < 256; off <<= 1) {
        int t = (threadIdx.x >= off) ? s[threadIdx.x - off] : 0;
        __syncthreads();
        s[threadIdx.x] += t;
        __syncthreads();
    }
    if (i < n) offs[i] = s[threadIdx.x] - v;
    if (threadIdx.x == 255) bsums[blockIdx.x] = s[255];
}

__global__ void scan_sums(int* __restrict__ bsums, int nb) {
    __shared__ int s[256];
    int v = (threadIdx.x < nb) ? bsums[threadIdx.x] : 0;
    s[threadIdx.x] = v; __syncthreads();
    #pragma unroll
    for (int off = 1; off < 256; off <<= 1) {
        int t = (threadIdx.x >= off) ? s[threadIdx.x - off] : 0;
        __syncthreads();
        s[threadIdx.x] += t;
        __syncthreads();
    }
    if (threadIdx.x < nb) bsums[threadIdx.x] = s[threadIdx.x] - v;
}

__global__ void scan_add(int* __restrict__ offs, int* __restrict__ cursor,
                         const int* __restrict__ bsums, int n, int total) {
    int i = blockIdx.x * 256 + threadIdx.x;
    if (i < n) {
        int o = offs[i] + bsums[i >> 8];
        offs[i] = o;
        cursor[i] = o;
    }
    if (i == 0) offs[n] = total;
}

__global__ void scatter_kernel(const int* __restrict__ src, const int* __restrict__ dst,
                               int* __restrict__ cursor, int* __restrict__ csr_src, int E) {
    int e = blockIdx.x * 256 + threadIdx.x;
    if (e < E) {
        int d = dst[e];
        int pos = atomicAdd(&cursor[d], 1);
        csr_src[pos] = src[e];
    }
}

// ---------------- W prep (all 3 layers in one dispatch) ----------------
__global__ void wprep3_kernel(const float* __restrict__ W0, const float* __restrict__ W1,
                              const float* __restrict__ W2,
                              ushort* __restrict__ Wh0, ushort* __restrict__ Wl0,
                              ushort* __restrict__ Wh1, ushort* __restrict__ Wl1,
                              ushort* __restrict__ Wh2, ushort* __restrict__ Wl2) {
    const float* W = (blockIdx.y == 0) ? W0 : (blockIdx.y == 1) ? W1 : W2;
    ushort* Wh = (blockIdx.y == 0) ? Wh0 : (blockIdx.y == 1) ? Wh1 : Wh2;
    ushort* Wl = (blockIdx.y == 0) ? Wl0 : (blockIdx.y == 1) ? Wl1 : Wl2;
    int n = blockIdx.x;
    int k = threadIdx.x;
    float v = W[(size_t)k * FEAT + n];
    ushort h = f2bf(v);
    float r = v - bf2f(h);
    Wh[(size_t)n * FEAT + k] = h;
    Wl[(size_t)n * FEAT + k] = f2bf(r);
}

// ---------------- fsplit: f32 row-major -> hi/lo bf16 (elementwise) ----------------
__global__ void fsplit_kernel(const float* __restrict__ A, ushort* __restrict__ Ah,
                              ushort* __restrict__ Al, int total8) {
    int i = blockIdx.x * 256 + threadIdx.x;
    if (i >= total8) return;
    const float4* p = (const float4*)(A + (size_t)i * 8);
    float4 a = p[0], b = p[1];
    float v[8] = {a.x, a.y, a.z, a.w, b.x, b.y, b.z, b.w};
    ushort hi[8], lo[8];
    #pragma unroll
    for (int t = 0; t < 8; ++t) {
        hi[t] = f2bf(v[t]);
        lo[t] = f2bf(v[t] - bf2f(hi[t]));
    }
    *(short8*)(Ah + (size_t)i * 8) = *(short8*)hi;
    *(short8*)(Al + (size_t)i * 8) = *(short8*)lo;
}

// ---------------- fused GEMM 128x256: A dbuf in LDS, B global->reg ----------------
// 4 waves; wave w owns cols [64w,64w+64) == head w, ALL 128 rows (acc[8][4]).
#define GBM 128
#define GBK 32
#define LDK 40   // padded K stride in ushorts (80 B rows)
#define NKIT (FEAT / GBK)   // 8

__global__ __launch_bounds__(256) void gemm_fused(const ushort* __restrict__ Ahg,
                                                  const ushort* __restrict__ Alg,
                                                  const ushort* __restrict__ Whg,
                                                  const ushort* __restrict__ Wlg,
                                                  const float* __restrict__ alv,
                                                  const float* __restrict__ arv,
                                                  ushort* __restrict__ featB,
                                                  float* __restrict__ el,
                                                  float* __restrict__ er, int M) {
    __shared__ ushort Ah[2][GBM][LDK];
    __shared__ ushort Al[2][GBM][LDK];

    const int tid  = threadIdx.x;
    const int lane = tid & 63;
    const int wid  = tid >> 6;          // wave == head == col block
    const int row0 = blockIdx.x * GBM;

    const int arow = tid >> 1;          // A stage row 0..127
    const int achk = (tid & 1) * 16;    // A stage k chunk (16 ushorts)
    const bool aok = (row0 + arow) < M;
    const ushort* ApH = Ahg + (size_t)(row0 + arow) * FEAT + achk;
    const ushort* ApL = Alg + (size_t)(row0 + arow) * FEAT + achk;

    const int fr = lane & 15;
    const int fk = (lane >> 4) * 8;
    const int q  = lane >> 4;

    f32x4 acc[8][4];
    #pragma unroll
    for (int i = 0; i < 8; ++i)
        #pragma unroll
        for (int j = 0; j < 4; ++j) {
            f32x4 z = {0.f, 0.f, 0.f, 0.f};
            acc[i][j] = z;
        }

    const short8 z8 = {0, 0, 0, 0, 0, 0, 0, 0};

    // prologue: stage k-iter 0 into buffer 0
    {
        short8 h0 = aok ? *(const short8*)(ApH)     : z8;
        short8 h1 = aok ? *(const short8*)(ApH + 8) : z8;
        short8 l0 = aok ? *(const short8*)(ApL)     : z8;
        short8 l1 = aok ? *(const short8*)(ApL + 8) : z8;
        *(short8*)&Ah[0][arow][achk]     = h0;
        *(short8*)&Ah[0][arow][achk + 8] = h1;
        *(short8*)&Al[0][arow][achk]     = l0;
        *(short8*)&Al[0][arow][achk + 8] = l1;
    }

    #pragma unroll
    for (int t = 0; t < NKIT; ++t) {
        const int cur = t & 1;
        const int k0 = t * GBK;
        // prefetch next A tile (regs)
        short8 h0 = z8, h1 = z8, l0 = z8, l1 = z8;
        if (t + 1 < NKIT && aok) {
            h0 = *(const short8*)(ApH + k0 + GBK);
            h1 = *(const short8*)(ApH + k0 + GBK + 8);
            l0 = *(const short8*)(ApL + k0 + GBK);
            l1 = *(const short8*)(ApL + k0 + GBK + 8);
        }
        // B fragments straight from global (W is L2-resident, [n][k] layout)
        short8 bfh[4], bfl[4];
        #pragma unroll
        for (int nt = 0; nt < 4; ++nt) {
            size_t boff = (size_t)(wid * 64 + nt * 16 + fr) * FEAT + k0 + fk;
            bfh[nt] = *(const short8*)(Whg + boff);
            bfl[nt] = *(const short8*)(Wlg + boff);
        }

        __syncthreads();

        #pragma unroll
        for (int mt = 0; mt < 8; ++mt) {
            short8 afh = *(const short8*)&Ah[cur][mt * 16 + fr][fk];
            short8 afl = *(const short8*)&Al[cur][mt * 16 + fr][fk];
            #pragma unroll
            for (int nt = 0; nt < 4; ++nt) {
                acc[mt][nt] = __builtin_amdgcn_mfma_f32_16x16x32_bf16(
                    afh, bfh[nt], acc[mt][nt], 0, 0, 0);
                acc[mt][nt] = __builtin_amdgcn_mfma_f32_16x16x32_bf16(
                    afh, bfl[nt], acc[mt][nt], 0, 0, 0);
                acc[mt][nt] = __builtin_amdgcn_mfma_f32_16x16x32_bf16(
                    afl, bfh[nt], acc[mt][nt], 0, 0, 0);
            }
        }
        if (t + 1 < NKIT) {
            *(short8*)&Ah[cur ^ 1][arow][achk]     = h0;
            *(short8*)&Ah[cur ^ 1][arow][achk + 8] = h1;
            *(short8*)&Al[cur ^ 1][arow][achk]     = l0;
            *(short8*)&Al[cur ^ 1][arow][achk + 8] = l1;
        }
    }

    // ---- epilogue: featB (bf16) + el/er for this wave's head ----
    float al4[4], ar4[4];
    #pragma unroll
    for (int nt = 0; nt < 4; ++nt) {
        al4[nt] = alv[wid * 64 + nt * 16 + fr];
        ar4[nt] = arv[wid * 64 + nt * 16 + fr];
    }
    #pragma unroll
    for (int mt = 0; mt < 8; ++mt) {
        #pragma unroll
        for (int r = 0; r < 4; ++r) {
            int row = row0 + mt * 16 + q * 4 + r;
            bool ok = row < M;
            float pl = 0.f, pr = 0.f;
            #pragma unroll
            for (int nt = 0; nt < 4; ++nt) {
                float v = acc[mt][nt][r];
                if (ok) featB[(size_t)row * FEAT + wid * 64 + nt * 16 + fr] = f2bf(v);
                pl = fmaf(v, al4[nt], pl);
                pr = fmaf(v, ar4[nt], pr);
            }
            #pragma unroll
            for (int o = 1; o < 16; o <<= 1) {
                pl += __shfl_xor(pl, o, 64);
                pr += __shfl_xor(pr, o, 64);
            }
            if (ok && fr == 0) {
                el[(size_t)row * NHEAD + wid] = pl;
                er[(size_t)row * NHEAD + wid] = pr;
            }
        }
    }
}

// ---------------- online-softmax aggregate, 2 edges per 16B load ----------------
// One wave per node. e-phase: lane = 16h + j16 computes e/w for head h, slot j16
// (16-edge chunks, unchanged). Gather phase: parity par=lane>>5 handles edges
// j0 = 2i+par; lane covers 8 feats at fb = (lane&31)*8 (32 lanes x 16B = full row).
// Acc head hh = (lane&31)>>3; w fetched from e-phase lane hh*16+j0 (w=0 for
// masked slots). Epilogue: cross-parity shfl_xor(32) sum, par==0 lanes store.
__global__ __launch_bounds__(256) void agg_kernel5(const ushort* __restrict__ featB,
                                                   const float* __restrict__ el,
                                                   const float* __restrict__ er,
                                                   const int* __restrict__ offs,
                                                   const int* __restrict__ csr_src,
                                                   const float* __restrict__ bias,
                                                   float* __restrict__ outF,
                                                   ushort* __restrict__ outH,
                                                   ushort* __restrict__ outL,
                                                   int act, int n) {
    int node = blockIdx.x * 4 + (threadIdx.x >> 6);
    if (node >= n) return;
    int lane = threadIdx.x & 63;
    int h   = lane >> 4;        // e-phase head
    int j16 = lane & 15;        // e-phase edge slot
    int l31 = lane & 31;
    int par = lane >> 5;        // gather edge parity
    int fb  = l31 * 8;          // 8 contiguous feats
    int hh  = l31 >> 3;         // head my accumulators belong to
    int start = offs[node];
    int deg = offs[node + 1] - start;
    float erh = er[node * NHEAD + h];

    float m = -1e30f, ssum = 0.f;
    float a0 = 0.f, a1 = 0.f, a2 = 0.f, a3 = 0.f;
    float a4 = 0.f, a5 = 0.f, a6 = 0.f, a7 = 0.f;
    int sidx = (j16 < deg) ? csr_src[start + j16] : 0;

    for (int p0 = 0; p0 < deg; p0 += 16) {
        int pn = p0 + 16 + j16;
        int sidx_nx = (pn < deg) ? csr_src[start + pn] : 0;   // prefetch next chunk
        float e = -1e30f;
        if (p0 + j16 < deg) {
            float t = el[sidx * NHEAD + h] + erh;
            e = (t > 0.f) ? t : 0.2f * t;
        }
        float cm = e;
        #pragma unroll
        for (int o = 1; o < 16; o <<= 1) cm = fmaxf(cm, __shfl_xor(cm, o, 64));
        float newm = fmaxf(m, cm);
        float sc = __expf(m - newm);   // uniform within e-phase head group
        m = newm;
        ssum *= sc;
        float w = __expf(e - m);       // masked slots: exp(-inf) = 0
        ssum += w;
        float scA = __shfl(sc, hh * 16, 64);   // sc of my ACC head
        a0 *= scA; a1 *= scA; a2 *= scA; a3 *= scA;
        a4 *= scA; a5 *= scA; a6 *= scA; a7 *= scA;
        int cnt = min(16, deg - p0);
        int iters = (cnt + 1) >> 1;
        for (int i = 0; i < iters; ++i) {
            int j0 = 2 * i + par;                    // my parity's edge slot
            int sj = __shfl(sidx, j0, 16);           // same across head groups
            float wj = __shfl(w, hh * 16 + j0, 64);  // w(acc-head, edge j0); 0 if masked
            short8 v = *(const short8*)(featB + (size_t)sj * FEAT + fb);
            a0 = fmaf(wj, bf2f((ushort)v[0]), a0);
            a1 = fmaf(wj, bf2f((ushort)v[1]), a1);
            a2 = fmaf(wj, bf2f((ushort)v[2]), a2);
            a3 = fmaf(wj, bf2f((ushort)v[3]), a3);
            a4 = fmaf(wj, bf2f((ushort)v[4]), a4);
            a5 = fmaf(wj, bf2f((ushort)v[5]), a5);
            a6 = fmaf(wj, bf2f((ushort)v[6]), a6);
            a7 = fmaf(wj, bf2f((ushort)v[7]), a7);
        }
        sidx = sidx_nx;
    }
    // ---- cross-parity combine (other half at lane^32) ----
    a0 += __shfl_xor(a0, 32, 64);
    a1 += __shfl_xor(a1, 32, 64);
    a2 += __shfl_xor(a2, 32, 64);
    a3 += __shfl_xor(a3, 32, 64);
    a4 += __shfl_xor(a4, 32, 64);
    a5 += __shfl_xor(a5, 32, 64);
    a6 += __shfl_xor(a6, 32, 64);
    a7 += __shfl_xor(a7, 32, 64);

    float st = ssum;
    #pragma unroll
    for (int o = 1; o < 16; o <<= 1) st += __shfl_xor(st, o, 64);
    float stA = __shfl(st, hh * 16, 64);   // denom of my ACC head
    if (par == 0) {
        float inv = 1.f / fmaxf(stA, 1e-9f);
        float4 b0 = *(const float4*)(bias + fb);
        float4 b1 = *(const float4*)(bias + fb + 4);
        float o0 = fmaf(a0, inv, b0.x);
        float o1 = fmaf(a1, inv, b0.y);
        float o2 = fmaf(a2, inv, b0.z);
        float o3 = fmaf(a3, inv, b0.w);
        float o4 = fmaf(a4, inv, b1.x);
        float o5 = fmaf(a5, inv, b1.y);
        float o6 = fmaf(a6, inv, b1.z);
        float o7 = fmaf(a7, inv, b1.w);
        if (act) {
            o0 = (o0 > 0.f) ? o0 : expm1f(o0);
            o1 = (o1 > 0.f) ? o1 : expm1f(o1);
            o2 = (o2 > 0.f) ? o2 : expm1f(o2);
            o3 = (o3 > 0.f) ? o3 : expm1f(o3);
            o4 = (o4 > 0.f) ? o4 : expm1f(o4);
            o5 = (o5 > 0.f) ? o5 : expm1f(o5);
            o6 = (o6 > 0.f) ? o6 : expm1f(o6);
            o7 = (o7 > 0.f) ? o7 : expm1f(o7);
        }
        if (outF) {
            *((float4*)(outF + (size_t)node * FEAT + fb))     = make_float4(o0, o1, o2, o3);
            *((float4*)(outF + (size_t)node * FEAT + fb + 4)) = make_float4(o4, o5, o6, o7);
        } else {
            ushort hi[8], lo[8];
            float ov[8] = {o0, o1, o2, o3, o4, o5, o6, o7};
            #pragma unroll
            for (int k = 0; k < 8; ++k) {
                hi[k] = f2bf(ov[k]);
                lo[k] = f2bf(ov[k] - bf2f(hi[k]));
            }
            *(short8*)(outH + (size_t)node * FEAT + fb) = *(short8*)hi;
            *(short8*)(outL + (size_t)node * FEAT + fb) = *(short8*)lo;
        }
    }
}

// ---------------------------------------------------------------------------
extern "C" void kernel_launch(void* const* d_in, const int* in_sizes, int n_in,
                              void* d_out, int out_size, void* d_ws, size_t ws_size,
                              hipStream_t stream) {
    const float* features = (const float*)d_in[0];
    const int*   src      = (const int*)d_in[1];
    const int*   dst      = (const int*)d_in[2];
    const int N = in_sizes[0] / FEAT;
    const int E = in_sizes[1];

    // ---- carve workspace ----
    char* ws = (char*)d_ws;
    size_t off = 0;
    auto carve = [&](size_t bytes) -> void* {
        void* p = ws + off;
        off = (off + bytes + 255) & ~(size_t)255;
        return p;
    };
    int*    deg     = (int*)carve((size_t)N * 4);
    int*    offs    = (int*)carve((size_t)(N + 1) * 4);
    int*    cursor  = (int*)carve((size_t)N * 4);
    int*    bsums   = (int*)carve(4096);
    int*    csr_src = (int*)carve((size_t)E * 4);
    float*  el      = (float*)carve((size_t)N * NHEAD * 4);
    float*  er      = (float*)carve((size_t)N * NHEAD * 4);
    ushort* featB   = (ushort*)carve((size_t)N * FEAT * 2);
    ushort* inAh    = (ushort*)carve((size_t)N * FEAT * 2);
    ushort* inAl    = (ushort*)carve((size_t)N * FEAT * 2);
    ushort* Wh[3], *Wl[3];
    for (int i = 0; i < 3; ++i) {
        Wh[i] = (ushort*)carve((size_t)FEAT * FEAT * 2);
        Wl[i] = (ushort*)carve((size_t)FEAT * FEAT * 2);
    }

    const int nbE = (E + 255) / 256;
    const int nbN = (N + 255) / 256;

    // ---- CSR build + W prep + feature split ----
    hipMemsetAsync(deg, 0, (size_t)N * 4, stream);
    hist_kernel<<<nbE, 256, 0, stream>>>(dst, deg, E);
    scan_block<<<nbN, 256, 0, stream>>>(deg, offs, bsums, N);
    scan_sums<<<1, 256, 0, stream>>>(bsums, nbN);
    scan_add<<<nbN, 256, 0, stream>>>(offs, cursor, bsums, N, E);
    scatter_kernel<<<nbE, 256, 0, stream>>>(src, dst, cursor, csr_src, E);
    dim3 wgrid(FEAT, 3);
    wprep3_kernel<<<wgrid, FEAT, 0, stream>>>((const float*)d_in[3], (const float*)d_in[7],
                                              (const float*)d_in[11],
                                              Wh[0], Wl[0], Wh[1], Wl[1], Wh[2], Wl[2]);
    const int total8 = N * FEAT / 8;
    fsplit_kernel<<<(total8 + 255) / 256, 256, 0, stream>>>(features, inAh, inAl, total8);

    const int gemmBlocks = (N + GBM - 1) / GBM;
    const int nodeBlocks = (N + 3) / 4;

    // ---- layer 1 ----
    gemm_fused<<<gemmBlocks, 256, 0, stream>>>(inAh, inAl, Wh[0], Wl[0],
                                               (const float*)d_in[4], (const float*)d_in[5],
                                               featB, el, er, N);
    agg_kernel5<<<nodeBlocks, 256, 0, stream>>>(featB, el, er, offs, csr_src,
                                                (const float*)d_in[6],
                                                (float*)nullptr, inAh, inAl, 1, N);
    // ---- layer 2 ----
    gemm_fused<<<gemmBlocks, 256, 0, stream>>>(inAh, inAl, Wh[1], Wl[1],
                                               (const float*)d_in[8], (const float*)d_in[9],
                                               featB, el, er, N);
    agg_kernel5<<<nodeBlocks, 256, 0, stream>>>(featB, el, er, offs, csr_src,
                                                (const float*)d_in[10],
                                                (float*)nullptr, inAh, inAl, 1, N);
    // ---- layer 3 ----
    gemm_fused<<<gemmBlocks, 256, 0, stream>>>(inAh, inAl, Wh[2], Wl[2],
                                               (const float*)d_in[12], (const float*)d_in[13],
                                               featB, el, er, N);
    agg_kernel5<<<nodeBlocks, 256, 0, stream>>>(featB, el, er, offs, csr_src,
                                                (const float*)d_in[14],
                                                (float*)d_out, (ushort*)nullptr, (ushort*)nullptr, 0, N);
}

// Round 17
// 444.858 us; speedup vs baseline: 1.2651x; 1.0654x over previous
//
#include <hip/hip_runtime.h>
#include <hip/hip_bf16.h>
#include <cstdint>

// ---------------------------------------------------------------------------
// GAT 3-layer forward. N=50000, E=800000, H=4, D=64 (FEAT = H*D = 256 = F_IN).
// R17: (1) GEMM back to measured-best GBM=64/acc[4][4]/dbuf (R16's GBM=128 cost
//      ~6us/dispatch via VGPR->occupancy); (2) layer-1 GEMM reads f32 features
//      and splits hi/lo inline during LDS staging -> fsplit pass deleted (~20us);
//      (3) agg_kernel5 (72us, measured) unchanged.
// ---------------------------------------------------------------------------

#define FEAT 256
#define NHEAD 4

typedef short short8 __attribute__((ext_vector_type(8)));
typedef float f32x4 __attribute__((ext_vector_type(4)));

__device__ __forceinline__ ushort f2bf(float v) {
    uint u = __float_as_uint(v);
    uint r = (u + 0x7fffu + ((u >> 16) & 1u)) >> 16;
    return (ushort)r;
}
__device__ __forceinline__ float bf2f(ushort h) {
    return __uint_as_float(((uint)h) << 16);
}

// ---------------- CSR build ----------------
__global__ void hist_kernel(const int* __restrict__ dst, int* __restrict__ deg, int E) {
    int e = blockIdx.x * 256 + threadIdx.x;
    if (e < E) atomicAdd(&deg[dst[e]], 1);
}

__global__ void scan_block(const int* __restrict__ deg, int* __restrict__ offs,
                           int* __restrict__ bsums, int n) {
    __shared__ int s[256];
    int i = blockIdx.x * 256 + threadIdx.x;
    int v = (i < n) ? deg[i] : 0;
    s[threadIdx.x] = v; __syncthreads();
    #pragma unroll
    for (int off = 1; off < 256; off <<= 1) {
        int t = (threadIdx.x >= off) ? s[threadIdx.x - off] : 0;
        __syncthreads();
        s[threadIdx.x] += t;
        __syncthreads();
    }
    if (i < n) offs[i] = s[threadIdx.x] - v;
    if (threadIdx.x == 255) bsums[blockIdx.x] = s[255];
}

__global__ void scan_sums(int* __restrict__ bsums, int nb) {
    __shared__ int s[256];
    int v = (threadIdx.x < nb) ? bsums[threadIdx.x] : 0;
    s[threadIdx.x] = v; __syncthreads();
    #pragma unroll
    for (int off = 1; off < 256; off <<= 1) {
        int t = (threadIdx.x >= off) ? s[threadIdx.x - off] : 0;
        __syncthreads();
        s[threadIdx.x] += t;
        __syncthreads();
    }
    if (threadIdx.x < nb) bsums[threadIdx.x] = s[threadIdx.x] - v;
}

__global__ void scan_add(int* __restrict__ offs, int* __restrict__ cursor,
                         const int* __restrict__ bsums, int n, int total) {
    int i = blockIdx.x * 256 + threadIdx.x;
    if (i < n) {
        int o = offs[i] + bsums[i >> 8];
        offs[i] = o;
        cursor[i] = o;
    }
    if (i == 0) offs[n] = total;
}

__global__ void scatter_kernel(const int* __restrict__ src, const int* __restrict__ dst,
                               int* __restrict__ cursor, int* __restrict__ csr_src, int E) {
    int e = blockIdx.x * 256 + threadIdx.x;
    if (e < E) {
        int d = dst[e];
        int pos = atomicAdd(&cursor[d], 1);
        csr_src[pos] = src[e];
    }
}

// ---------------- W prep (all 3 layers in one dispatch) ----------------
__global__ void wprep3_kernel(const float* __restrict__ W0, const float* __restrict__ W1,
                              const float* __restrict__ W2,
                              ushort* __restrict__ Wh0, ushort* __restrict__ Wl0,
                              ushort* __restrict__ Wh1, ushort* __restrict__ Wl1,
                              ushort* __restrict__ Wh2, ushort* __restrict__ Wl2) {
    const float* W = (blockIdx.y == 0) ? W0 : (blockIdx.y == 1) ? W1 : W2;
    ushort* Wh = (blockIdx.y == 0) ? Wh0 : (blockIdx.y == 1) ? Wh1 : Wh2;
    ushort* Wl = (blockIdx.y == 0) ? Wl0 : (blockIdx.y == 1) ? Wl1 : Wl2;
    int n = blockIdx.x;
    int k = threadIdx.x;
    float v = W[(size_t)k * FEAT + n];
    ushort h = f2bf(v);
    float r = v - bf2f(h);
    Wh[(size_t)n * FEAT + k] = h;
    Wl[(size_t)n * FEAT + k] = f2bf(r);
}

// ---------------- fused GEMM 64x256: A dbuf in LDS, B global->reg ----------------
// 4 waves; wave w owns cols [64w,64w+64) == head w. One barrier per k-iter.
#define GBM 64
#define GBK 32
#define LDK 40   // padded K stride in ushorts (80 B rows)
#define NKIT (FEAT / GBK)   // 8

__global__ __launch_bounds__(256) void gemm_fused(const ushort* __restrict__ Ahg,
                                                  const ushort* __restrict__ Alg,
                                                  const ushort* __restrict__ Whg,
                                                  const ushort* __restrict__ Wlg,
                                                  const float* __restrict__ alv,
                                                  const float* __restrict__ arv,
                                                  ushort* __restrict__ featB,
                                                  float* __restrict__ el,
                                                  float* __restrict__ er, int M) {
    __shared__ ushort Ah[2][GBM][LDK];
    __shared__ ushort Al[2][GBM][LDK];

    const int tid  = threadIdx.x;
    const int lane = tid & 63;
    const int wid  = tid >> 6;          // wave == head == col block
    const int row0 = blockIdx.x * GBM;

    const int arow = tid >> 2;          // A stage row 0..63
    const int achk = (tid & 3) * 8;     // A stage k chunk (ushort offset)
    const bool aok = (row0 + arow) < M;
    const ushort* ApH = Ahg + (size_t)(row0 + arow) * FEAT + achk;
    const ushort* ApL = Alg + (size_t)(row0 + arow) * FEAT + achk;

    const int fr = lane & 15;
    const int fk = (lane >> 4) * 8;
    const int q  = lane >> 4;

    f32x4 acc[4][4];
    #pragma unroll
    for (int i = 0; i < 4; ++i)
        #pragma unroll
        for (int j = 0; j < 4; ++j) {
            f32x4 z = {0.f, 0.f, 0.f, 0.f};
            acc[i][j] = z;
        }

    const short8 z8 = {0, 0, 0, 0, 0, 0, 0, 0};

    // prologue: stage k-iter 0 into buffer 0
    {
        short8 a_h = aok ? *(const short8*)(ApH) : z8;
        short8 a_l = aok ? *(const short8*)(ApL) : z8;
        *(short8*)&Ah[0][arow][achk] = a_h;
        *(short8*)&Al[0][arow][achk] = a_l;
    }

    #pragma unroll
    for (int t = 0; t < NKIT; ++t) {
        const int cur = t & 1;
        const int k0 = t * GBK;
        // prefetch next A tile (regs) -- hides under this iter's MFMA
        short8 a_h = z8, a_l = z8;
        if (t + 1 < NKIT && aok) {
            a_h = *(const short8*)(ApH + k0 + GBK);
            a_l = *(const short8*)(ApL + k0 + GBK);
        }
        // B fragments straight from global (W is L2-resident, [n][k] layout)
        short8 bfh[4], bfl[4];
        #pragma unroll
        for (int nt = 0; nt < 4; ++nt) {
            size_t boff = (size_t)(wid * 64 + nt * 16 + fr) * FEAT + k0 + fk;
            bfh[nt] = *(const short8*)(Whg + boff);
            bfl[nt] = *(const short8*)(Wlg + boff);
        }

        __syncthreads();   // buf[cur] writes visible; prior reads of buf[cur^1] done

        #pragma unroll
        for (int mt = 0; mt < 4; ++mt) {
            short8 afh = *(const short8*)&Ah[cur][mt * 16 + fr][fk];
            short8 afl = *(const short8*)&Al[cur][mt * 16 + fr][fk];
            #pragma unroll
            for (int nt = 0; nt < 4; ++nt) {
                acc[mt][nt] = __builtin_amdgcn_mfma_f32_16x16x32_bf16(
                    afh, bfh[nt], acc[mt][nt], 0, 0, 0);
                acc[mt][nt] = __builtin_amdgcn_mfma_f32_16x16x32_bf16(
                    afh, bfl[nt], acc[mt][nt], 0, 0, 0);
                acc[mt][nt] = __builtin_amdgcn_mfma_f32_16x16x32_bf16(
                    afl, bfh[nt], acc[mt][nt], 0, 0, 0);
            }
        }
        if (t + 1 < NKIT) {
            *(short8*)&Ah[cur ^ 1][arow][achk] = a_h;
            *(short8*)&Al[cur ^ 1][arow][achk] = a_l;
        }
    }

    // ---- epilogue: featB (bf16) + el/er for this wave's head ----
    float al4[4], ar4[4];
    #pragma unroll
    for (int nt = 0; nt < 4; ++nt) {
        al4[nt] = alv[wid * 64 + nt * 16 + fr];
        ar4[nt] = arv[wid * 64 + nt * 16 + fr];
    }
    #pragma unroll
    for (int mt = 0; mt < 4; ++mt) {
        #pragma unroll
        for (int r = 0; r < 4; ++r) {
            int row = row0 + mt * 16 + q * 4 + r;
            bool ok = row < M;
            float pl = 0.f, pr = 0.f;
            #pragma unroll
            for (int nt = 0; nt < 4; ++nt) {
                float v = acc[mt][nt][r];
                if (ok) featB[(size_t)row * FEAT + wid * 64 + nt * 16 + fr] = f2bf(v);
                pl = fmaf(v, al4[nt], pl);
                pr = fmaf(v, ar4[nt], pr);
            }
            #pragma unroll
            for (int o = 1; o < 16; o <<= 1) {
                pl += __shfl_xor(pl, o, 64);
                pr += __shfl_xor(pr, o, 64);
            }
            if (ok && fr == 0) {
                el[(size_t)row * NHEAD + wid] = pl;
                er[(size_t)row * NHEAD + wid] = pr;
            }
        }
    }
}

// ---------------- layer-1 GEMM: f32 A input, hi/lo split inline at staging ------
__global__ __launch_bounds__(256) void gemm_fused_f32a(const float* __restrict__ Af,
                                                       const ushort* __restrict__ Whg,
                                                       const ushort* __restrict__ Wlg,
                                                       const float* __restrict__ alv,
                                                       const float* __restrict__ arv,
                                                       ushort* __restrict__ featB,
                                                       float* __restrict__ el,
                                                       float* __restrict__ er, int M) {
    __shared__ ushort Ah[2][GBM][LDK];
    __shared__ ushort Al[2][GBM][LDK];

    const int tid  = threadIdx.x;
    const int lane = tid & 63;
    const int wid  = tid >> 6;
    const int row0 = blockIdx.x * GBM;

    const int arow = tid >> 2;
    const int achk = (tid & 3) * 8;
    const bool aok = (row0 + arow) < M;
    const float* Ap = Af + (size_t)(row0 + arow) * FEAT + achk;

    const int fr = lane & 15;
    const int fk = (lane >> 4) * 8;
    const int q  = lane >> 4;

    f32x4 acc[4][4];
    #pragma unroll
    for (int i = 0; i < 4; ++i)
        #pragma unroll
        for (int j = 0; j < 4; ++j) {
            f32x4 z = {0.f, 0.f, 0.f, 0.f};
            acc[i][j] = z;
        }

    const float4 z4 = make_float4(0.f, 0.f, 0.f, 0.f);

    auto split_store = [&](int buf, float4 f0, float4 f1) {
        float v[8] = {f0.x, f0.y, f0.z, f0.w, f1.x, f1.y, f1.z, f1.w};
        ushort hi[8], lo[8];
        #pragma unroll
        for (int k = 0; k < 8; ++k) {
            hi[k] = f2bf(v[k]);
            lo[k] = f2bf(v[k] - bf2f(hi[k]));
        }
        *(short8*)&Ah[buf][arow][achk] = *(short8*)hi;
        *(short8*)&Al[buf][arow][achk] = *(short8*)lo;
    };

    // prologue: stage k-iter 0 into buffer 0
    {
        float4 f0 = aok ? *(const float4*)(Ap)     : z4;
        float4 f1 = aok ? *(const float4*)(Ap + 4) : z4;
        split_store(0, f0, f1);
    }

    #pragma unroll
    for (int t = 0; t < NKIT; ++t) {
        const int cur = t & 1;
        const int k0 = t * GBK;
        float4 f0 = z4, f1 = z4;
        if (t + 1 < NKIT && aok) {
            f0 = *(const float4*)(Ap + k0 + GBK);
            f1 = *(const float4*)(Ap + k0 + GBK + 4);
        }
        short8 bfh[4], bfl[4];
        #pragma unroll
        for (int nt = 0; nt < 4; ++nt) {
            size_t boff = (size_t)(wid * 64 + nt * 16 + fr) * FEAT + k0 + fk;
            bfh[nt] = *(const short8*)(Whg + boff);
            bfl[nt] = *(const short8*)(Wlg + boff);
        }

        __syncthreads();

        #pragma unroll
        for (int mt = 0; mt < 4; ++mt) {
            short8 afh = *(const short8*)&Ah[cur][mt * 16 + fr][fk];
            short8 afl = *(const short8*)&Al[cur][mt * 16 + fr][fk];
            #pragma unroll
            for (int nt = 0; nt < 4; ++nt) {
                acc[mt][nt] = __builtin_amdgcn_mfma_f32_16x16x32_bf16(
                    afh, bfh[nt], acc[mt][nt], 0, 0, 0);
                acc[mt][nt] = __builtin_amdgcn_mfma_f32_16x16x32_bf16(
                    afh, bfl[nt], acc[mt][nt], 0, 0, 0);
                acc[mt][nt] = __builtin_amdgcn_mfma_f32_16x16x32_bf16(
                    afl, bfh[nt], acc[mt][nt], 0, 0, 0);
            }
        }
        if (t + 1 < NKIT) split_store(cur ^ 1, f0, f1);
    }

    // ---- epilogue: featB (bf16) + el/er for this wave's head ----
    float al4[4], ar4[4];
    #pragma unroll
    for (int nt = 0; nt < 4; ++nt) {
        al4[nt] = alv[wid * 64 + nt * 16 + fr];
        ar4[nt] = arv[wid * 64 + nt * 16 + fr];
    }
    #pragma unroll
    for (int mt = 0; mt < 4; ++mt) {
        #pragma unroll
        for (int r = 0; r < 4; ++r) {
            int row = row0 + mt * 16 + q * 4 + r;
            bool ok = row < M;
            float pl = 0.f, pr = 0.f;
            #pragma unroll
            for (int nt = 0; nt < 4; ++nt) {
                float v = acc[mt][nt][r];
                if (ok) featB[(size_t)row * FEAT + wid * 64 + nt * 16 + fr] = f2bf(v);
                pl = fmaf(v, al4[nt], pl);
                pr = fmaf(v, ar4[nt], pr);
            }
            #pragma unroll
            for (int o = 1; o < 16; o <<= 1) {
                pl += __shfl_xor(pl, o, 64);
                pr += __shfl_xor(pr, o, 64);
            }
            if (ok && fr == 0) {
                el[(size_t)row * NHEAD + wid] = pl;
                er[(size_t)row * NHEAD + wid] = pr;
            }
        }
    }
}

// ---------------- online-softmax aggregate, 2 edges per 16B load ----------------
// One wave per node. e-phase: lane = 16h + j16 computes e/w for head h, slot j16.
// Gather: parity par=lane>>5 handles edges j0=2i+par; lane covers 8 feats at
// fb=(lane&31)*8; acc head hh=(lane&31)>>3; w from e-phase lane hh*16+j0.
// Epilogue: cross-parity shfl_xor(32) sum, par==0 lanes store.
__global__ __launch_bounds__(256) void agg_kernel5(const ushort* __restrict__ featB,
                                                   const float* __restrict__ el,
                                                   const float* __restrict__ er,
                                                   const int* __restrict__ offs,
                                                   const int* __restrict__ csr_src,
                                                   const float* __restrict__ bias,
                                                   float* __restrict__ outF,
                                                   ushort* __restrict__ outH,
                                                   ushort* __restrict__ outL,
                                                   int act, int n) {
    int node = blockIdx.x * 4 + (threadIdx.x >> 6);
    if (node >= n) return;
    int lane = threadIdx.x & 63;
    int h   = lane >> 4;
    int j16 = lane & 15;
    int l31 = lane & 31;
    int par = lane >> 5;
    int fb  = l31 * 8;
    int hh  = l31 >> 3;
    int start = offs[node];
    int deg = offs[node + 1] - start;
    float erh = er[node * NHEAD + h];

    float m = -1e30f, ssum = 0.f;
    float a0 = 0.f, a1 = 0.f, a2 = 0.f, a3 = 0.f;
    float a4 = 0.f, a5 = 0.f, a6 = 0.f, a7 = 0.f;
    int sidx = (j16 < deg) ? csr_src[start + j16] : 0;

    for (int p0 = 0; p0 < deg; p0 += 16) {
        int pn = p0 + 16 + j16;
        int sidx_nx = (pn < deg) ? csr_src[start + pn] : 0;
        float e = -1e30f;
        if (p0 + j16 < deg) {
            float t = el[sidx * NHEAD + h] + erh;
            e = (t > 0.f) ? t : 0.2f * t;
        }
        float cm = e;
        #pragma unroll
        for (int o = 1; o < 16; o <<= 1) cm = fmaxf(cm, __shfl_xor(cm, o, 64));
        float newm = fmaxf(m, cm);
        float sc = __expf(m - newm);
        m = newm;
        ssum *= sc;
        float w = __expf(e - m);
        ssum += w;
        float scA = __shfl(sc, hh * 16, 64);
        a0 *= scA; a1 *= scA; a2 *= scA; a3 *= scA;
        a4 *= scA; a5 *= scA; a6 *= scA; a7 *= scA;
        int cnt = min(16, deg - p0);
        int iters = (cnt + 1) >> 1;
        for (int i = 0; i < iters; ++i) {
            int j0 = 2 * i + par;
            int sj = __shfl(sidx, j0, 16);
            float wj = __shfl(w, hh * 16 + j0, 64);
            short8 v = *(const short8*)(featB + (size_t)sj * FEAT + fb);
            a0 = fmaf(wj, bf2f((ushort)v[0]), a0);
            a1 = fmaf(wj, bf2f((ushort)v[1]), a1);
            a2 = fmaf(wj, bf2f((ushort)v[2]), a2);
            a3 = fmaf(wj, bf2f((ushort)v[3]), a3);
            a4 = fmaf(wj, bf2f((ushort)v[4]), a4);
            a5 = fmaf(wj, bf2f((ushort)v[5]), a5);
            a6 = fmaf(wj, bf2f((ushort)v[6]), a6);
            a7 = fmaf(wj, bf2f((ushort)v[7]), a7);
        }
        sidx = sidx_nx;
    }
    a0 += __shfl_xor(a0, 32, 64);
    a1 += __shfl_xor(a1, 32, 64);
    a2 += __shfl_xor(a2, 32, 64);
    a3 += __shfl_xor(a3, 32, 64);
    a4 += __shfl_xor(a4, 32, 64);
    a5 += __shfl_xor(a5, 32, 64);
    a6 += __shfl_xor(a6, 32, 64);
    a7 += __shfl_xor(a7, 32, 64);

    float st = ssum;
    #pragma unroll
    for (int o = 1; o < 16; o <<= 1) st += __shfl_xor(st, o, 64);
    float stA = __shfl(st, hh * 16, 64);
    if (par == 0) {
        float inv = 1.f / fmaxf(stA, 1e-9f);
        float4 b0 = *(const float4*)(bias + fb);
        float4 b1 = *(const float4*)(bias + fb + 4);
        float o0 = fmaf(a0, inv, b0.x);
        float o1 = fmaf(a1, inv, b0.y);
        float o2 = fmaf(a2, inv, b0.z);
        float o3 = fmaf(a3, inv, b0.w);
        float o4 = fmaf(a4, inv, b1.x);
        float o5 = fmaf(a5, inv, b1.y);
        float o6 = fmaf(a6, inv, b1.z);
        float o7 = fmaf(a7, inv, b1.w);
        if (act) {
            o0 = (o0 > 0.f) ? o0 : expm1f(o0);
            o1 = (o1 > 0.f) ? o1 : expm1f(o1);
            o2 = (o2 > 0.f) ? o2 : expm1f(o2);
            o3 = (o3 > 0.f) ? o3 : expm1f(o3);
            o4 = (o4 > 0.f) ? o4 : expm1f(o4);
            o5 = (o5 > 0.f) ? o5 : expm1f(o5);
            o6 = (o6 > 0.f) ? o6 : expm1f(o6);
            o7 = (o7 > 0.f) ? o7 : expm1f(o7);
        }
        if (outF) {
            *((float4*)(outF + (size_t)node * FEAT + fb))     = make_float4(o0, o1, o2, o3);
            *((float4*)(outF + (size_t)node * FEAT + fb + 4)) = make_float4(o4, o5, o6, o7);
        } else {
            ushort hi[8], lo[8];
            float ov[8] = {o0, o1, o2, o3, o4, o5, o6, o7};
            #pragma unroll
            for (int k = 0; k < 8; ++k) {
                hi[k] = f2bf(ov[k]);
                lo[k] = f2bf(ov[k] - bf2f(hi[k]));
            }
            *(short8*)(outH + (size_t)node * FEAT + fb) = *(short8*)hi;
            *(short8*)(outL + (size_t)node * FEAT + fb) = *(short8*)lo;
        }
    }
}

// ---------------------------------------------------------------------------
extern "C" void kernel_launch(void* const* d_in, const int* in_sizes, int n_in,
                              void* d_out, int out_size, void* d_ws, size_t ws_size,
                              hipStream_t stream) {
    const float* features = (const float*)d_in[0];
    const int*   src      = (const int*)d_in[1];
    const int*   dst      = (const int*)d_in[2];
    const int N = in_sizes[0] / FEAT;
    const int E = in_sizes[1];

    // ---- carve workspace ----
    char* ws = (char*)d_ws;
    size_t off = 0;
    auto carve = [&](size_t bytes) -> void* {
        void* p = ws + off;
        off = (off + bytes + 255) & ~(size_t)255;
        return p;
    };
    int*    deg     = (int*)carve((size_t)N * 4);
    int*    offs    = (int*)carve((size_t)(N + 1) * 4);
    int*    cursor  = (int*)carve((size_t)N * 4);
    int*    bsums   = (int*)carve(4096);
    int*    csr_src = (int*)carve((size_t)E * 4);
    float*  el      = (float*)carve((size_t)N * NHEAD * 4);
    float*  er      = (float*)carve((size_t)N * NHEAD * 4);
    ushort* featB   = (ushort*)carve((size_t)N * FEAT * 2);
    ushort* inAh    = (ushort*)carve((size_t)N * FEAT * 2);
    ushort* inAl    = (ushort*)carve((size_t)N * FEAT * 2);
    ushort* Wh[3], *Wl[3];
    for (int i = 0; i < 3; ++i) {
        Wh[i] = (ushort*)carve((size_t)FEAT * FEAT * 2);
        Wl[i] = (ushort*)carve((size_t)FEAT * FEAT * 2);
    }

    const int nbE = (E + 255) / 256;
    const int nbN = (N + 255) / 256;

    // ---- CSR build + W prep ----
    hipMemsetAsync(deg, 0, (size_t)N * 4, stream);
    hist_kernel<<<nbE, 256, 0, stream>>>(dst, deg, E);
    scan_block<<<nbN, 256, 0, stream>>>(deg, offs, bsums, N);
    scan_sums<<<1, 256, 0, stream>>>(bsums, nbN);
    scan_add<<<nbN, 256, 0, stream>>>(offs, cursor, bsums, N, E);
    scatter_kernel<<<nbE, 256, 0, stream>>>(src, dst, cursor, csr_src, E);
    dim3 wgrid(FEAT, 3);
    wprep3_kernel<<<wgrid, FEAT, 0, stream>>>((const float*)d_in[3], (const float*)d_in[7],
                                              (const float*)d_in[11],
                                              Wh[0], Wl[0], Wh[1], Wl[1], Wh[2], Wl[2]);

    const int gemmBlocks = (N + GBM - 1) / GBM;
    const int nodeBlocks = (N + 3) / 4;

    // ---- layer 1 (f32 features, inline split) ----
    gemm_fused_f32a<<<gemmBlocks, 256, 0, stream>>>(features, Wh[0], Wl[0],
                                                    (const float*)d_in[4], (const float*)d_in[5],
                                                    featB, el, er, N);
    agg_kernel5<<<nodeBlocks, 256, 0, stream>>>(featB, el, er, offs, csr_src,
                                                (const float*)d_in[6],
                                                (float*)nullptr, inAh, inAl, 1, N);
    // ---- layer 2 ----
    gemm_fused<<<gemmBlocks, 256, 0, stream>>>(inAh, inAl, Wh[1], Wl[1],
                                               (const float*)d_in[8], (const float*)d_in[9],
                                               featB, el, er, N);
    agg_kernel5<<<nodeBlocks, 256, 0, stream>>>(featB, el, er, offs, csr_src,
                                                (const float*)d_in[10],
                                                (float*)nullptr, inAh, inAl, 1, N);
    // ---- layer 3 ----
    gemm_fused<<<gemmBlocks, 256, 0, stream>>>(inAh, inAl, Wh[2], Wl[2],
                                               (const float*)d_in[12], (const float*)d_in[13],
                                               featB, el, er, N);
    agg_kernel5<<<nodeBlocks, 256, 0, stream>>>(featB, el, er, offs, csr_src,
                                                (const float*)d_in[14],
                                                (float*)d_out, (ushort*)nullptr, (ushort*)nullptr, 0, N);
}

// Round 18
// 443.366 us; speedup vs baseline: 1.2694x; 1.0034x over previous
//
#include <hip/hip_runtime.h>
#include <hip/hip_bf16.h>
#include <cstdint>

// ---------------------------------------------------------------------------
// GAT 3-layer forward. N=50000, E=800000, H=4, D=64 (FEAT = H*D = 256 = F_IN).
// R18: GEMM epilogue rewritten (both variants): acc -> bf16 -> LDS[64][264]
//      transpose -> fully-coalesced 16B-piece stores (R17 post-mortem: 64
//      scalar 2B stores/thread = 4x32B segments/instr dominated gemm's 62us).
//      el/er + k-loop + agg_kernel5 unchanged (all measured-best).
// ---------------------------------------------------------------------------

#define FEAT 256
#define NHEAD 4

typedef short short8 __attribute__((ext_vector_type(8)));
typedef float f32x4 __attribute__((ext_vector_type(4)));

__device__ __forceinline__ ushort f2bf(float v) {
    uint u = __float_as_uint(v);
    uint r = (u + 0x7fffu + ((u >> 16) & 1u)) >> 16;
    return (ushort)r;
}
__device__ __forceinline__ float bf2f(ushort h) {
    return __uint_as_float(((uint)h) << 16);
}

// ---------------- CSR build ----------------
__global__ void hist_kernel(const int* __restrict__ dst, int* __restrict__ deg, int E) {
    int e = blockIdx.x * 256 + threadIdx.x;
    if (e < E) atomicAdd(&deg[dst[e]], 1);
}

__global__ void scan_block(const int* __restrict__ deg, int* __restrict__ offs,
                           int* __restrict__ bsums, int n) {
    __shared__ int s[256];
    int i = blockIdx.x * 256 + threadIdx.x;
    int v = (i < n) ? deg[i] : 0;
    s[threadIdx.x] = v; __syncthreads();
    #pragma unroll
    for (int off = 1; off < 256; off <<= 1) {
        int t = (threadIdx.x >= off) ? s[threadIdx.x - off] : 0;
        __syncthreads();
        s[threadIdx.x] += t;
        __syncthreads();
    }
    if (i < n) offs[i] = s[threadIdx.x] - v;
    if (threadIdx.x == 255) bsums[blockIdx.x] = s[255];
}

__global__ void scan_sums(int* __restrict__ bsums, int nb) {
    __shared__ int s[256];
    int v = (threadIdx.x < nb) ? bsums[threadIdx.x] : 0;
    s[threadIdx.x] = v; __syncthreads();
    #pragma unroll
    for (int off = 1; off < 256; off <<= 1) {
        int t = (threadIdx.x >= off) ? s[threadIdx.x - off] : 0;
        __syncthreads();
        s[threadIdx.x] += t;
        __syncthreads();
    }
    if (threadIdx.x < nb) bsums[threadIdx.x] = s[threadIdx.x] - v;
}

__global__ void scan_add(int* __restrict__ offs, int* __restrict__ cursor,
                         const int* __restrict__ bsums, int n, int total) {
    int i = blockIdx.x * 256 + threadIdx.x;
    if (i < n) {
        int o = offs[i] + bsums[i >> 8];
        offs[i] = o;
        cursor[i] = o;
    }
    if (i == 0) offs[n] = total;
}

__global__ void scatter_kernel(const int* __restrict__ src, const int* __restrict__ dst,
                               int* __restrict__ cursor, int* __restrict__ csr_src, int E) {
    int e = blockIdx.x * 256 + threadIdx.x;
    if (e < E) {
        int d = dst[e];
        int pos = atomicAdd(&cursor[d], 1);
        csr_src[pos] = src[e];
    }
}

// ---------------- W prep (all 3 layers in one dispatch) ----------------
__global__ void wprep3_kernel(const float* __restrict__ W0, const float* __restrict__ W1,
                              const float* __restrict__ W2,
                              ushort* __restrict__ Wh0, ushort* __restrict__ Wl0,
                              ushort* __restrict__ Wh1, ushort* __restrict__ Wl1,
                              ushort* __restrict__ Wh2, ushort* __restrict__ Wl2) {
    const float* W = (blockIdx.y == 0) ? W0 : (blockIdx.y == 1) ? W1 : W2;
    ushort* Wh = (blockIdx.y == 0) ? Wh0 : (blockIdx.y == 1) ? Wh1 : Wh2;
    ushort* Wl = (blockIdx.y == 0) ? Wl0 : (blockIdx.y == 1) ? Wl1 : Wl2;
    int n = blockIdx.x;
    int k = threadIdx.x;
    float v = W[(size_t)k * FEAT + n];
    ushort h = f2bf(v);
    float r = v - bf2f(h);
    Wh[(size_t)n * FEAT + k] = h;
    Wl[(size_t)n * FEAT + k] = f2bf(r);
}

// ---------------- fused GEMM 64x256: A dbuf in LDS, B global->reg ----------------
// 4 waves; wave w owns cols [64w,64w+64) == head w. One barrier per k-iter.
// Epilogue: el/er shuffle-reduce from regs, then LDS bf16 transpose ->
// fully-coalesced 16B-piece featB stores.
#define GBM 64
#define GBK 32
#define LDK 40    // padded K stride in ushorts (80 B rows)
#define NKIT (FEAT / GBK)   // 8
#define TLD 264   // epilogue transpose row stride (ushorts): 528 B, 16B-aligned

// smem ushorts: k-loop needs 2*2*64*40 = 10240; epilogue needs 64*264 = 16896.
#define SMEM_USHORTS 16896

__device__ __forceinline__ void gemm_epilogue(ushort* smem, f32x4 (*acc)[4],
                                              const float* alv, const float* arv,
                                              ushort* featB, float* el, float* er,
                                              int row0, int wid, int lane, int tid, int M) {
    const int fr = lane & 15;
    const int q  = lane >> 4;
    // ---- el/er from regs (16-lane group shuffle reduce) ----
    float al4[4], ar4[4];
    #pragma unroll
    for (int nt = 0; nt < 4; ++nt) {
        al4[nt] = alv[wid * 64 + nt * 16 + fr];
        ar4[nt] = arv[wid * 64 + nt * 16 + fr];
    }
    #pragma unroll
    for (int mt = 0; mt < 4; ++mt) {
        #pragma unroll
        for (int r = 0; r < 4; ++r) {
            int row = row0 + mt * 16 + q * 4 + r;
            bool ok = row < M;
            float pl = 0.f, pr = 0.f;
            #pragma unroll
            for (int nt = 0; nt < 4; ++nt) {
                float v = acc[mt][nt][r];
                pl = fmaf(v, al4[nt], pl);
                pr = fmaf(v, ar4[nt], pr);
            }
            #pragma unroll
            for (int o = 1; o < 16; o <<= 1) {
                pl += __shfl_xor(pl, o, 64);
                pr += __shfl_xor(pr, o, 64);
            }
            if (ok && fr == 0) {
                el[(size_t)row * NHEAD + wid] = pl;
                er[(size_t)row * NHEAD + wid] = pr;
            }
        }
    }
    // ---- transpose via LDS: dump bf16, then coalesced 16B-piece stores ----
    __syncthreads();   // all waves done reading k-loop LDS buffers
    ushort (*T)[TLD] = (ushort(*)[TLD])smem;
    #pragma unroll
    for (int mt = 0; mt < 4; ++mt) {
        #pragma unroll
        for (int nt = 0; nt < 4; ++nt) {
            #pragma unroll
            for (int r = 0; r < 4; ++r) {
                int row = mt * 16 + q * 4 + r;
                T[row][wid * 64 + nt * 16 + fr] = f2bf(acc[mt][nt][r]);
            }
        }
    }
    __syncthreads();
    // 64 rows x 512 B = 2048 pieces of 16B; piece p = j*256 + tid.
    #pragma unroll
    for (int j = 0; j < 8; ++j) {
        int p = j * 256 + tid;
        int row = p >> 5;
        int pc = p & 31;
        if (row0 + row < M) {
            short8 v = *(const short8*)&T[row][pc * 8];
            *(short8*)(featB + (size_t)(row0 + row) * FEAT + pc * 8) = v;
        }
    }
}

__global__ __launch_bounds__(256) void gemm_fused(const ushort* __restrict__ Ahg,
                                                  const ushort* __restrict__ Alg,
                                                  const ushort* __restrict__ Whg,
                                                  const ushort* __restrict__ Wlg,
                                                  const float* __restrict__ alv,
                                                  const float* __restrict__ arv,
                                                  ushort* __restrict__ featB,
                                                  float* __restrict__ el,
                                                  float* __restrict__ er, int M) {
    __shared__ ushort smem[SMEM_USHORTS];
    ushort (*Ah)[GBM][LDK] = (ushort(*)[GBM][LDK])smem;
    ushort (*Al)[GBM][LDK] = (ushort(*)[GBM][LDK])(smem + 2 * GBM * LDK);

    const int tid  = threadIdx.x;
    const int lane = tid & 63;
    const int wid  = tid >> 6;
    const int row0 = blockIdx.x * GBM;

    const int arow = tid >> 2;
    const int achk = (tid & 3) * 8;
    const bool aok = (row0 + arow) < M;
    const ushort* ApH = Ahg + (size_t)(row0 + arow) * FEAT + achk;
    const ushort* ApL = Alg + (size_t)(row0 + arow) * FEAT + achk;

    const int fr = lane & 15;
    const int fk = (lane >> 4) * 8;

    f32x4 acc[4][4];
    #pragma unroll
    for (int i = 0; i < 4; ++i)
        #pragma unroll
        for (int j = 0; j < 4; ++j) {
            f32x4 z = {0.f, 0.f, 0.f, 0.f};
            acc[i][j] = z;
        }

    const short8 z8 = {0, 0, 0, 0, 0, 0, 0, 0};

    {
        short8 a_h = aok ? *(const short8*)(ApH) : z8;
        short8 a_l = aok ? *(const short8*)(ApL) : z8;
        *(short8*)&Ah[0][arow][achk] = a_h;
        *(short8*)&Al[0][arow][achk] = a_l;
    }

    #pragma unroll
    for (int t = 0; t < NKIT; ++t) {
        const int cur = t & 1;
        const int k0 = t * GBK;
        short8 a_h = z8, a_l = z8;
        if (t + 1 < NKIT && aok) {
            a_h = *(const short8*)(ApH + k0 + GBK);
            a_l = *(const short8*)(ApL + k0 + GBK);
        }
        short8 bfh[4], bfl[4];
        #pragma unroll
        for (int nt = 0; nt < 4; ++nt) {
            size_t boff = (size_t)(wid * 64 + nt * 16 + fr) * FEAT + k0 + fk;
            bfh[nt] = *(const short8*)(Whg + boff);
            bfl[nt] = *(const short8*)(Wlg + boff);
        }

        __syncthreads();

        #pragma unroll
        for (int mt = 0; mt < 4; ++mt) {
            short8 afh = *(const short8*)&Ah[cur][mt * 16 + fr][fk];
            short8 afl = *(const short8*)&Al[cur][mt * 16 + fr][fk];
            #pragma unroll
            for (int nt = 0; nt < 4; ++nt) {
                acc[mt][nt] = __builtin_amdgcn_mfma_f32_16x16x32_bf16(
                    afh, bfh[nt], acc[mt][nt], 0, 0, 0);
                acc[mt][nt] = __builtin_amdgcn_mfma_f32_16x16x32_bf16(
                    afh, bfl[nt], acc[mt][nt], 0, 0, 0);
                acc[mt][nt] = __builtin_amdgcn_mfma_f32_16x16x32_bf16(
                    afl, bfh[nt], acc[mt][nt], 0, 0, 0);
            }
        }
        if (t + 1 < NKIT) {
            *(short8*)&Ah[cur ^ 1][arow][achk] = a_h;
            *(short8*)&Al[cur ^ 1][arow][achk] = a_l;
        }
    }

    gemm_epilogue(smem, acc, alv, arv, featB, el, er, row0, wid, lane, tid, M);
}

// ---------------- layer-1 GEMM: f32 A input, hi/lo split inline at staging ------
__global__ __launch_bounds__(256) void gemm_fused_f32a(const float* __restrict__ Af,
                                                       const ushort* __restrict__ Whg,
                                                       const ushort* __restrict__ Wlg,
                                                       const float* __restrict__ alv,
                                                       const float* __restrict__ arv,
                                                       ushort* __restrict__ featB,
                                                       float* __restrict__ el,
                                                       float* __restrict__ er, int M) {
    __shared__ ushort smem[SMEM_USHORTS];
    ushort (*Ah)[GBM][LDK] = (ushort(*)[GBM][LDK])smem;
    ushort (*Al)[GBM][LDK] = (ushort(*)[GBM][LDK])(smem + 2 * GBM * LDK);

    const int tid  = threadIdx.x;
    const int lane = tid & 63;
    const int wid  = tid >> 6;
    const int row0 = blockIdx.x * GBM;

    const int arow = tid >> 2;
    const int achk = (tid & 3) * 8;
    const bool aok = (row0 + arow) < M;
    const float* Ap = Af + (size_t)(row0 + arow) * FEAT + achk;

    const int fr = lane & 15;
    const int fk = (lane >> 4) * 8;

    f32x4 acc[4][4];
    #pragma unroll
    for (int i = 0; i < 4; ++i)
        #pragma unroll
        for (int j = 0; j < 4; ++j) {
            f32x4 z = {0.f, 0.f, 0.f, 0.f};
            acc[i][j] = z;
        }

    const float4 z4 = make_float4(0.f, 0.f, 0.f, 0.f);

    auto split_store = [&](int buf, float4 f0, float4 f1) {
        float v[8] = {f0.x, f0.y, f0.z, f0.w, f1.x, f1.y, f1.z, f1.w};
        ushort hi[8], lo[8];
        #pragma unroll
        for (int k = 0; k < 8; ++k) {
            hi[k] = f2bf(v[k]);
            lo[k] = f2bf(v[k] - bf2f(hi[k]));
        }
        *(short8*)&Ah[buf][arow][achk] = *(short8*)hi;
        *(short8*)&Al[buf][arow][achk] = *(short8*)lo;
    };

    {
        float4 f0 = aok ? *(const float4*)(Ap)     : z4;
        float4 f1 = aok ? *(const float4*)(Ap + 4) : z4;
        split_store(0, f0, f1);
    }

    #pragma unroll
    for (int t = 0; t < NKIT; ++t) {
        const int cur = t & 1;
        const int k0 = t * GBK;
        float4 f0 = z4, f1 = z4;
        if (t + 1 < NKIT && aok) {
            f0 = *(const float4*)(Ap + k0 + GBK);
            f1 = *(const float4*)(Ap + k0 + GBK + 4);
        }
        short8 bfh[4], bfl[4];
        #pragma unroll
        for (int nt = 0; nt < 4; ++nt) {
            size_t boff = (size_t)(wid * 64 + nt * 16 + fr) * FEAT + k0 + fk;
            bfh[nt] = *(const short8*)(Whg + boff);
            bfl[nt] = *(const short8*)(Wlg + boff);
        }

        __syncthreads();

        #pragma unroll
        for (int mt = 0; mt < 4; ++mt) {
            short8 afh = *(const short8*)&Ah[cur][mt * 16 + fr][fk];
            short8 afl = *(const short8*)&Al[cur][mt * 16 + fr][fk];
            #pragma unroll
            for (int nt = 0; nt < 4; ++nt) {
                acc[mt][nt] = __builtin_amdgcn_mfma_f32_16x16x32_bf16(
                    afh, bfh[nt], acc[mt][nt], 0, 0, 0);
                acc[mt][nt] = __builtin_amdgcn_mfma_f32_16x16x32_bf16(
                    afh, bfl[nt], acc[mt][nt], 0, 0, 0);
                acc[mt][nt] = __builtin_amdgcn_mfma_f32_16x16x32_bf16(
                    afl, bfh[nt], acc[mt][nt], 0, 0, 0);
            }
        }
        if (t + 1 < NKIT) split_store(cur ^ 1, f0, f1);
    }

    gemm_epilogue(smem, acc, alv, arv, featB, el, er, row0, wid, lane, tid, M);
}

// ---------------- online-softmax aggregate, 2 edges per 16B load ----------------
__global__ __launch_bounds__(256) void agg_kernel5(const ushort* __restrict__ featB,
                                                   const float* __restrict__ el,
                                                   const float* __restrict__ er,
                                                   const int* __restrict__ offs,
                                                   const int* __restrict__ csr_src,
                                                   const float* __restrict__ bias,
                                                   float* __restrict__ outF,
                                                   ushort* __restrict__ outH,
                                                   ushort* __restrict__ outL,
                                                   int act, int n) {
    int node = blockIdx.x * 4 + (threadIdx.x >> 6);
    if (node >= n) return;
    int lane = threadIdx.x & 63;
    int h   = lane >> 4;
    int j16 = lane & 15;
    int l31 = lane & 31;
    int par = lane >> 5;
    int fb  = l31 * 8;
    int hh  = l31 >> 3;
    int start = offs[node];
    int deg = offs[node + 1] - start;
    float erh = er[node * NHEAD + h];

    float m = -1e30f, ssum = 0.f;
    float a0 = 0.f, a1 = 0.f, a2 = 0.f, a3 = 0.f;
    float a4 = 0.f, a5 = 0.f, a6 = 0.f, a7 = 0.f;
    int sidx = (j16 < deg) ? csr_src[start + j16] : 0;

    for (int p0 = 0; p0 < deg; p0 += 16) {
        int pn = p0 + 16 + j16;
        int sidx_nx = (pn < deg) ? csr_src[start + pn] : 0;
        float e = -1e30f;
        if (p0 + j16 < deg) {
            float t = el[sidx * NHEAD + h] + erh;
            e = (t > 0.f) ? t : 0.2f * t;
        }
        float cm = e;
        #pragma unroll
        for (int o = 1; o < 16; o <<= 1) cm = fmaxf(cm, __shfl_xor(cm, o, 64));
        float newm = fmaxf(m, cm);
        float sc = __expf(m - newm);
        m = newm;
        ssum *= sc;
        float w = __expf(e - m);
        ssum += w;
        float scA = __shfl(sc, hh * 16, 64);
        a0 *= scA; a1 *= scA; a2 *= scA; a3 *= scA;
        a4 *= scA; a5 *= scA; a6 *= scA; a7 *= scA;
        int cnt = min(16, deg - p0);
        int iters = (cnt + 1) >> 1;
        for (int i = 0; i < iters; ++i) {
            int j0 = 2 * i + par;
            int sj = __shfl(sidx, j0, 16);
            float wj = __shfl(w, hh * 16 + j0, 64);
            short8 v = *(const short8*)(featB + (size_t)sj * FEAT + fb);
            a0 = fmaf(wj, bf2f((ushort)v[0]), a0);
            a1 = fmaf(wj, bf2f((ushort)v[1]), a1);
            a2 = fmaf(wj, bf2f((ushort)v[2]), a2);
            a3 = fmaf(wj, bf2f((ushort)v[3]), a3);
            a4 = fmaf(wj, bf2f((ushort)v[4]), a4);
            a5 = fmaf(wj, bf2f((ushort)v[5]), a5);
            a6 = fmaf(wj, bf2f((ushort)v[6]), a6);
            a7 = fmaf(wj, bf2f((ushort)v[7]), a7);
        }
        sidx = sidx_nx;
    }
    a0 += __shfl_xor(a0, 32, 64);
    a1 += __shfl_xor(a1, 32, 64);
    a2 += __shfl_xor(a2, 32, 64);
    a3 += __shfl_xor(a3, 32, 64);
    a4 += __shfl_xor(a4, 32, 64);
    a5 += __shfl_xor(a5, 32, 64);
    a6 += __shfl_xor(a6, 32, 64);
    a7 += __shfl_xor(a7, 32, 64);

    float st = ssum;
    #pragma unroll
    for (int o = 1; o < 16; o <<= 1) st += __shfl_xor(st, o, 64);
    float stA = __shfl(st, hh * 16, 64);
    if (par == 0) {
        float inv = 1.f / fmaxf(stA, 1e-9f);
        float4 b0 = *(const float4*)(bias + fb);
        float4 b1 = *(const float4*)(bias + fb + 4);
        float o0 = fmaf(a0, inv, b0.x);
        float o1 = fmaf(a1, inv, b0.y);
        float o2 = fmaf(a2, inv, b0.z);
        float o3 = fmaf(a3, inv, b0.w);
        float o4 = fmaf(a4, inv, b1.x);
        float o5 = fmaf(a5, inv, b1.y);
        float o6 = fmaf(a6, inv, b1.z);
        float o7 = fmaf(a7, inv, b1.w);
        if (act) {
            o0 = (o0 > 0.f) ? o0 : expm1f(o0);
            o1 = (o1 > 0.f) ? o1 : expm1f(o1);
            o2 = (o2 > 0.f) ? o2 : expm1f(o2);
            o3 = (o3 > 0.f) ? o3 : expm1f(o3);
            o4 = (o4 > 0.f) ? o4 : expm1f(o4);
            o5 = (o5 > 0.f) ? o5 : expm1f(o5);
            o6 = (o6 > 0.f) ? o6 : expm1f(o6);
            o7 = (o7 > 0.f) ? o7 : expm1f(o7);
        }
        if (outF) {
            *((float4*)(outF + (size_t)node * FEAT + fb))     = make_float4(o0, o1, o2, o3);
            *((float4*)(outF + (size_t)node * FEAT + fb + 4)) = make_float4(o4, o5, o6, o7);
        } else {
            ushort hi[8], lo[8];
            float ov[8] = {o0, o1, o2, o3, o4, o5, o6, o7};
            #pragma unroll
            for (int k = 0; k < 8; ++k) {
                hi[k] = f2bf(ov[k]);
                lo[k] = f2bf(ov[k] - bf2f(hi[k]));
            }
            *(short8*)(outH + (size_t)node * FEAT + fb) = *(short8*)hi;
            *(short8*)(outL + (size_t)node * FEAT + fb) = *(short8*)lo;
        }
    }
}

// ---------------------------------------------------------------------------
extern "C" void kernel_launch(void* const* d_in, const int* in_sizes, int n_in,
                              void* d_out, int out_size, void* d_ws, size_t ws_size,
                              hipStream_t stream) {
    const float* features = (const float*)d_in[0];
    const int*   src      = (const int*)d_in[1];
    const int*   dst      = (const int*)d_in[2];
    const int N = in_sizes[0] / FEAT;
    const int E = in_sizes[1];

    // ---- carve workspace ----
    char* ws = (char*)d_ws;
    size_t off = 0;
    auto carve = [&](size_t bytes) -> void* {
        void* p = ws + off;
        off = (off + bytes + 255) & ~(size_t)255;
        return p;
    };
    int*    deg     = (int*)carve((size_t)N * 4);
    int*    offs    = (int*)carve((size_t)(N + 1) * 4);
    int*    cursor  = (int*)carve((size_t)N * 4);
    int*    bsums   = (int*)carve(4096);
    int*    csr_src = (int*)carve((size_t)E * 4);
    float*  el      = (float*)carve((size_t)N * NHEAD * 4);
    float*  er      = (float*)carve((size_t)N * NHEAD * 4);
    ushort* featB   = (ushort*)carve((size_t)N * FEAT * 2);
    ushort* inAh    = (ushort*)carve((size_t)N * FEAT * 2);
    ushort* inAl    = (ushort*)carve((size_t)N * FEAT * 2);
    ushort* Wh[3], *Wl[3];
    for (int i = 0; i < 3; ++i) {
        Wh[i] = (ushort*)carve((size_t)FEAT * FEAT * 2);
        Wl[i] = (ushort*)carve((size_t)FEAT * FEAT * 2);
    }

    const int nbE = (E + 255) / 256;
    const int nbN = (N + 255) / 256;

    // ---- CSR build + W prep ----
    hipMemsetAsync(deg, 0, (size_t)N * 4, stream);
    hist_kernel<<<nbE, 256, 0, stream>>>(dst, deg, E);
    scan_block<<<nbN, 256, 0, stream>>>(deg, offs, bsums, N);
    scan_sums<<<1, 256, 0, stream>>>(bsums, nbN);
    scan_add<<<nbN, 256, 0, stream>>>(offs, cursor, bsums, N, E);
    scatter_kernel<<<nbE, 256, 0, stream>>>(src, dst, cursor, csr_src, E);
    dim3 wgrid(FEAT, 3);
    wprep3_kernel<<<wgrid, FEAT, 0, stream>>>((const float*)d_in[3], (const float*)d_in[7],
                                              (const float*)d_in[11],
                                              Wh[0], Wl[0], Wh[1], Wl[1], Wh[2], Wl[2]);

    const int gemmBlocks = (N + GBM - 1) / GBM;
    const int nodeBlocks = (N + 3) / 4;

    // ---- layer 1 (f32 features, inline split) ----
    gemm_fused_f32a<<<gemmBlocks, 256, 0, stream>>>(features, Wh[0], Wl[0],
                                                    (const float*)d_in[4], (const float*)d_in[5],
                                                    featB, el, er, N);
    agg_kernel5<<<nodeBlocks, 256, 0, stream>>>(featB, el, er, offs, csr_src,
                                                (const float*)d_in[6],
                                                (float*)nullptr, inAh, inAl, 1, N);
    // ---- layer 2 ----
    gemm_fused<<<gemmBlocks, 256, 0, stream>>>(inAh, inAl, Wh[1], Wl[1],
                                               (const float*)d_in[8], (const float*)d_in[9],
                                               featB, el, er, N);
    agg_kernel5<<<nodeBlocks, 256, 0, stream>>>(featB, el, er, offs, csr_src,
                                                (const float*)d_in[10],
                                                (float*)nullptr, inAh, inAl, 1, N);
    // ---- layer 3 ----
    gemm_fused<<<gemmBlocks, 256, 0, stream>>>(inAh, inAl, Wh[2], Wl[2],
                                               (const float*)d_in[12], (const float*)d_in[13],
                                               featB, el, er, N);
    agg_kernel5<<<nodeBlocks, 256, 0, stream>>>(featB, el, er, offs, csr_src,
                                                (const float*)d_in[14],
                                                (float*)d_out, (ushort*)nullptr, (ushort*)nullptr, 0, N);
}